// Round 1
// baseline (677.223 us; speedup 1.0000x reference)
//
#include <hip/hip_runtime.h>

typedef __bf16 bf16;
typedef __bf16 bf16x4 __attribute__((ext_vector_type(4)));
typedef __bf16 bf16x8 __attribute__((ext_vector_type(8)));
typedef float f32x4 __attribute__((ext_vector_type(4)));

#define S_LEN 2048
#define HID_DIM 4096
#define NH 32
#define NKV 8
#define HD 128
#define QKV_N 6144   // 4096 Q + 1024 K + 1024 V
#define K_COL 4096
#define V_COL 5120

// ---------------- fp32 -> bf16 conversion (vectorized) ----------------
__global__ void cvt_f32_bf16_kernel(const float* __restrict__ in, bf16* __restrict__ out, int n4) {
  int i = blockIdx.x * blockDim.x + threadIdx.x;
  if (i >= n4) return;
  float4 v = reinterpret_cast<const float4*>(in)[i];
  bf16x4 o;
  o[0] = (bf16)v.x; o[1] = (bf16)v.y; o[2] = (bf16)v.z; o[3] = (bf16)v.w;
  reinterpret_cast<bf16x4*>(out)[i] = o;
}

// ---------------- RoPE tables: cos/sin [S][64] fp32 ----------------
__global__ void rope_table_kernel(float* __restrict__ cost, float* __restrict__ sint) {
  int i = blockIdx.x * blockDim.x + threadIdx.x;   // 2048*64
  int s = i >> 6, d = i & 63;
  // inv_freq = 10000^(-d/64) = exp(-d * ln(10000)/64)
  float inv = expf(-0.14391156831212787f * (float)d);
  float ang = (float)s * inv;
  cost[i] = cosf(ang);
  sint[i] = sinf(ang);
}

// ---------------- RoPE apply in-place on Q,K halves of qkv ----------------
__global__ void rope_apply_kernel(bf16* __restrict__ qkv, const float* __restrict__ cost,
                                  const float* __restrict__ sint) {
  int idx = blockIdx.x * blockDim.x + threadIdx.x;  // 2048 * 2560 pairs
  int s = idx / 2560;
  int c = idx - s * 2560;
  int g = c >> 6, d = c & 63;            // g: 40 head-slots (32 Q + 8 K), contiguous cols 0..5119
  long base = (long)s * QKV_N + g * 128 + d;
  float x1 = (float)qkv[base], x2 = (float)qkv[base + 64];
  int ti = (s << 6) + d;
  float co = cost[ti], sn = sint[ti];
  qkv[base]      = (bf16)(x1 * co - x2 * sn);
  qkv[base + 64] = (bf16)(x2 * co + x1 * sn);
}

// ---------------- bf16 GEMM, C[M,N] = A[M,K] @ B[N,K]^T (m97 structure) ----------------
// 128x128 tile, BK=64, 4 waves (2x2), global_load_lds w=16, both-sides chunk XOR swizzle.
template<typename OutT>
__global__ __launch_bounds__(256, 2) void gemm_bt_kernel(
    const bf16* __restrict__ A, const bf16* __restrict__ B, OutT* __restrict__ C,
    int M, int N, int K) {
  __shared__ __align__(16) bf16 As[128 * 64];
  __shared__ __align__(16) bf16 Bs[128 * 64];

  // XCD-aware bijective swizzle (nwg % 8 == 0 for all our launches)
  int nwg = gridDim.x * gridDim.y;
  int bid = blockIdx.y * gridDim.x + blockIdx.x;
  int cpx = nwg >> 3;
  int swz = (bid & 7) * cpx + (bid >> 3);
  int bx = swz % gridDim.x, by = swz / gridDim.x;
  const int n0 = bx * 128, m0 = by * 128;

  const int t = threadIdx.x;
  const int lane = t & 63, w = t >> 6;
  const int wr = w >> 1, wc = w & 1;
  const int lg = lane >> 4, lm = lane & 15;
  f32x4 acc[4][4] = {};

  for (int k0 = 0; k0 < K; k0 += 64) {
    __syncthreads();
    // stage A,B tiles: 128 rows x 8 chunks(16B) each; LDS linear dest,
    // pre-swizzled global source (chunk jg = jl ^ (row&7)) -- rule #21.
#pragma unroll
    for (int i = 0; i < 4; ++i) {
      int c = i * 256 + t;
      int r = c >> 3, jl = c & 7;
      int jg = jl ^ (r & 7);
      const bf16* srcA = A + (long)(m0 + r) * K + k0 + jg * 8;
      __builtin_amdgcn_global_load_lds((const __attribute__((address_space(1))) void*)srcA,
                                       (__attribute__((address_space(3))) void*)(As + c * 8), 16, 0, 0);
      const bf16* srcB = B + (long)(n0 + r) * K + k0 + jg * 8;
      __builtin_amdgcn_global_load_lds((const __attribute__((address_space(1))) void*)srcB,
                                       (__attribute__((address_space(3))) void*)(Bs + c * 8), 16, 0, 0);
    }
    __syncthreads();
#pragma unroll
    for (int ks = 0; ks < 2; ++ks) {
      bf16x8 a[4], b[4];
#pragma unroll
      for (int m = 0; m < 4; ++m) {
        int r = wr * 64 + m * 16 + lm;
        int j = ks * 4 + lg;
        a[m] = *reinterpret_cast<const bf16x8*>(As + r * 64 + ((j ^ (r & 7)) << 3));
      }
#pragma unroll
      for (int n = 0; n < 4; ++n) {
        int r = wc * 64 + n * 16 + lm;
        int j = ks * 4 + lg;
        b[n] = *reinterpret_cast<const bf16x8*>(Bs + r * 64 + ((j ^ (r & 7)) << 3));
      }
#pragma unroll
      for (int m = 0; m < 4; ++m)
#pragma unroll
        for (int n = 0; n < 4; ++n)
          acc[m][n] = __builtin_amdgcn_mfma_f32_16x16x32_bf16(a[m], b[n], acc[m][n], 0, 0, 0);
    }
  }
  // epilogue: C/D layout col=lane&15, row=(lane>>4)*4+reg (m89-verified)
#pragma unroll
  for (int m = 0; m < 4; ++m) {
    int row = m0 + wr * 64 + m * 16 + lg * 4;
#pragma unroll
    for (int n = 0; n < 4; ++n) {
      int col = n0 + wc * 64 + n * 16 + lm;
#pragma unroll
      for (int r = 0; r < 4; ++r) {
        float v = acc[m][n][r];
        if constexpr (sizeof(OutT) == 4) C[(long)(row + r) * N + col] = v;
        else                             C[(long)(row + r) * N + col] = (bf16)v;
      }
    }
  }
}

// ---------------- GQA causal flash attention ----------------
// 4 waves x 16 q-rows = QBLK 64 per block; KVBLK=32; K padded [32][136], V transposed [128][40].
__global__ __launch_bounds__(256, 2) void attn_kernel(const bf16* __restrict__ qkv,
                                                      bf16* __restrict__ out) {
  __shared__ __align__(16) bf16 Ks[32 * 136];
  __shared__ __align__(16) bf16 Vt[128 * 40];
  __shared__ __align__(16) bf16 Pw[4 * 16 * 40];

  const int qb = blockIdx.x, h = blockIdx.y;
  const int kvh = h >> 2;               // GROUPS = 4
  const int q0 = qb * 64;
  const int t = threadIdx.x, lane = t & 63, w = t >> 6;
  const int lg = lane >> 4, lm = lane & 15;

  // Q fragments in registers: A-frag lane holds Q[row=lm][k=ks*32+lg*8+j]
  const long qrow = q0 + w * 16 + lm;
  bf16x8 qf[4];
#pragma unroll
  for (int ks = 0; ks < 4; ++ks)
    qf[ks] = *reinterpret_cast<const bf16x8*>(qkv + qrow * QKV_N + h * HD + ks * 32 + lg * 8);

  f32x4 o[8];
#pragma unroll
  for (int i = 0; i < 8; ++i) o[i] = f32x4{0.f, 0.f, 0.f, 0.f};
  float mrow[4] = {-1e30f, -1e30f, -1e30f, -1e30f};
  float lrow[4] = {0.f, 0.f, 0.f, 0.f};

  const int wave_max_row = q0 + w * 16 + 15;
  const int kv_end = q0 + 64;

  for (int kv0 = 0; kv0 < kv_end; kv0 += 32) {
    __syncthreads();
    // stage K [32][128] row-major(padded) and V transposed -> Vt[d][kv]
#pragma unroll
    for (int i = 0; i < 2; ++i) {
      int c = i * 256 + t;
      int kvr = c >> 4, jc = c & 15;
      bf16x8 kvv = *reinterpret_cast<const bf16x8*>(qkv + (long)(kv0 + kvr) * QKV_N + K_COL + kvh * HD + jc * 8);
      *reinterpret_cast<bf16x8*>(Ks + kvr * 136 + jc * 8) = kvv;
      bf16x8 vv = *reinterpret_cast<const bf16x8*>(qkv + (long)(kv0 + kvr) * QKV_N + V_COL + kvh * HD + jc * 8);
#pragma unroll
      for (int e = 0; e < 8; ++e)
        Vt[(jc * 8 + e) * 40 + kvr] = vv[e];
    }
    __syncthreads();
    if (kv0 <= wave_max_row) {          // wave-uniform causal skip
      // S = Q @ K^T, two 16-col blocks
      f32x4 s0 = {0.f,0.f,0.f,0.f}, s1 = {0.f,0.f,0.f,0.f};
#pragma unroll
      for (int ks = 0; ks < 4; ++ks) {
        bf16x8 k0f = *reinterpret_cast<const bf16x8*>(Ks + lm * 136 + ks * 32 + lg * 8);
        bf16x8 k1f = *reinterpret_cast<const bf16x8*>(Ks + (16 + lm) * 136 + ks * 32 + lg * 8);
        s0 = __builtin_amdgcn_mfma_f32_16x16x32_bf16(qf[ks], k0f, s0, 0, 0, 0);
        s1 = __builtin_amdgcn_mfma_f32_16x16x32_bf16(qf[ks], k1f, s1, 0, 0, 0);
      }
      // scale into log2 domain + causal mask
      const float SC = 0.12751742f;     // (1/sqrt(128)) * log2(e)
      float sl0[4], sl1[4];
      const int col0 = kv0 + lm, col1 = kv0 + 16 + lm;
#pragma unroll
      for (int r = 0; r < 4; ++r) {
        int row = q0 + w * 16 + lg * 4 + r;
        sl0[r] = (col0 <= row) ? s0[r] * SC : -1e30f;
        sl1[r] = (col1 <= row) ? s1[r] * SC : -1e30f;
      }
      // row max across 16 lanes
      float tm[4];
#pragma unroll
      for (int r = 0; r < 4; ++r) tm[r] = fmaxf(sl0[r], sl1[r]);
#pragma unroll
      for (int off = 1; off < 16; off <<= 1)
#pragma unroll
        for (int r = 0; r < 4; ++r) tm[r] = fmaxf(tm[r], __shfl_xor(tm[r], off));
      float alpha[4], p0[4], p1[4], psum[4];
#pragma unroll
      for (int r = 0; r < 4; ++r) {
        float mnew = fmaxf(mrow[r], tm[r]);
        alpha[r] = exp2f(mrow[r] - mnew);
        mrow[r] = mnew;
        p0[r] = exp2f(sl0[r] - mnew);
        p1[r] = exp2f(sl1[r] - mnew);
        psum[r] = p0[r] + p1[r];
      }
#pragma unroll
      for (int off = 1; off < 16; off <<= 1)
#pragma unroll
        for (int r = 0; r < 4; ++r) psum[r] += __shfl_xor(psum[r], off);
#pragma unroll
      for (int r = 0; r < 4; ++r) lrow[r] = lrow[r] * alpha[r] + psum[r];
#pragma unroll
      for (int i = 0; i < 8; ++i)
#pragma unroll
        for (int r = 0; r < 4; ++r) o[i][r] *= alpha[r];
      // P -> LDS (bf16), per-wave region
      bf16* pw = Pw + w * 16 * 40;
#pragma unroll
      for (int r = 0; r < 4; ++r) {
        pw[(lg * 4 + r) * 40 + lm]      = (bf16)p0[r];
        pw[(lg * 4 + r) * 40 + 16 + lm] = (bf16)p1[r];
      }
      // PV: A = P[16x32], B-frag from Vt rows (contiguous 16B)
      bf16x8 pa = *reinterpret_cast<const bf16x8*>(pw + lm * 40 + lg * 8);
#pragma unroll
      for (int db = 0; db < 8; ++db) {
        bf16x8 vf = *reinterpret_cast<const bf16x8*>(Vt + (db * 16 + lm) * 40 + lg * 8);
        o[db] = __builtin_amdgcn_mfma_f32_16x16x32_bf16(pa, vf, o[db], 0, 0, 0);
      }
    }
  }
  // epilogue: normalize and store bf16 [S][4096]
#pragma unroll
  for (int r = 0; r < 4; ++r) {
    float inv = 1.0f / lrow[r];
    long row = q0 + w * 16 + lg * 4 + r;
#pragma unroll
    for (int db = 0; db < 8; ++db)
      out[row * HID_DIM + h * HD + db * 16 + lm] = (bf16)(o[db][r] * inv);
  }
}

extern "C" void kernel_launch(void* const* d_in, const int* in_sizes, int n_in,
                              void* d_out, int out_size, void* d_ws, size_t ws_size,
                              hipStream_t stream) {
  const float* hs = (const float*)d_in[0];
  const float* Wq = (const float*)d_in[1];
  const float* Wk = (const float*)d_in[2];
  const float* Wv = (const float*)d_in[3];
  const float* Wo = (const float*)d_in[4];
  float* out = (float*)d_out;
  char* ws = (char*)d_ws;

  // workspace layout (total ~137 MB)
  bf16*  hsb   = (bf16*)(ws);                    // 2048x4096 bf16      (16 MB)
  bf16*  wqkvb = (bf16*)(ws + 16777216);         // 6144x4096 bf16      (50 MB)
  bf16*  wob   = (bf16*)(ws + 67108864);         // 4096x4096 bf16      (33 MB)
  bf16*  qkv   = (bf16*)(ws + 100663296);        // 2048x6144 bf16      (25 MB)
  bf16*  attn  = (bf16*)(ws + 125829120);        // 2048x4096 bf16      (16 MB)
  float* cost  = (float*)(ws + 142606336);       // 2048x64 f32
  float* sint  = (float*)(ws + 143130624);       // 2048x64 f32

  // 1) casts
  cvt_f32_bf16_kernel<<<8192,  256, 0, stream>>>(hs, hsb, 2097152);
  cvt_f32_bf16_kernel<<<16384, 256, 0, stream>>>(Wq, wqkvb, 4194304);
  cvt_f32_bf16_kernel<<<4096,  256, 0, stream>>>(Wk, wqkvb + (long)4096 * 4096, 1048576);
  cvt_f32_bf16_kernel<<<4096,  256, 0, stream>>>(Wv, wqkvb + (long)5120 * 4096, 1048576);
  cvt_f32_bf16_kernel<<<16384, 256, 0, stream>>>(Wo, wob, 4194304);
  rope_table_kernel<<<512, 256, 0, stream>>>(cost, sint);
  // 2) fused QKV projection
  gemm_bt_kernel<bf16><<<dim3(48, 16), 256, 0, stream>>>(hsb, wqkvb, qkv, 2048, 6144, 4096);
  // 3) RoPE in place on Q,K
  rope_apply_kernel<<<20480, 256, 0, stream>>>(qkv, cost, sint);
  // 4) attention
  attn_kernel<<<dim3(32, 32), 256, 0, stream>>>(qkv, attn);
  // 5) output projection (fp32 out)
  gemm_bt_kernel<float><<<dim3(32, 16), 256, 0, stream>>>(attn, wob, out, 2048, 4096, 4096);
}

// Round 2
// 382.985 us; speedup vs baseline: 1.7683x; 1.7683x over previous
//
#include <hip/hip_runtime.h>

typedef __bf16 bf16;
typedef __bf16 bf16x4 __attribute__((ext_vector_type(4)));
typedef __bf16 bf16x8 __attribute__((ext_vector_type(8)));
typedef float f32x4 __attribute__((ext_vector_type(4)));

#define S_LEN 2048
#define HID_DIM 4096
#define NH 32
#define NKV 8
#define HD 128
#define QKV_N 6144   // 4096 Q + 1024 K + 1024 V
#define K_COL 4096
#define V_COL 5120
#define PADV 76
#define PADP 72

// ---------------- fp32 -> bf16 conversion (vectorized) ----------------
__global__ void cvt_f32_bf16_kernel(const float* __restrict__ in, bf16* __restrict__ out, int n4) {
  int i = blockIdx.x * blockDim.x + threadIdx.x;
  if (i >= n4) return;
  float4 v = reinterpret_cast<const float4*>(in)[i];
  bf16x4 o;
  o[0] = (bf16)v.x; o[1] = (bf16)v.y; o[2] = (bf16)v.z; o[3] = (bf16)v.w;
  reinterpret_cast<bf16x4*>(out)[i] = o;
}

// ---------------- RoPE tables: cos/sin [S][64] fp32 ----------------
__global__ void rope_table_kernel(float* __restrict__ cost, float* __restrict__ sint) {
  int i = blockIdx.x * blockDim.x + threadIdx.x;   // 2048*64
  int s = i >> 6, d = i & 63;
  float inv = expf(-0.14391156831212787f * (float)d);   // 10000^(-d/64)
  float ang = (float)s * inv;
  cost[i] = cosf(ang);
  sint[i] = sinf(ang);
}

// ---------------- RoPE apply in-place on Q,K halves of qkv ----------------
__global__ void rope_apply_kernel(bf16* __restrict__ qkv, const float* __restrict__ cost,
                                  const float* __restrict__ sint) {
  int idx = blockIdx.x * blockDim.x + threadIdx.x;  // 2048 * 2560 pairs
  int s = idx / 2560;
  int c = idx - s * 2560;
  int g = c >> 6, d = c & 63;            // 40 head-slots (32 Q + 8 K), cols 0..5119
  long base = (long)s * QKV_N + g * 128 + d;
  float x1 = (float)qkv[base], x2 = (float)qkv[base + 64];
  int ti = (s << 6) + d;
  float co = cost[ti], sn = sint[ti];
  qkv[base]      = (bf16)(x1 * co - x2 * sn);
  qkv[base + 64] = (bf16)(x2 * co + x1 * sn);
}

// ---------------- bf16 GEMM, C[M,N] = A[M,K] @ B[N,K]^T (m97 structure) ----------------
template<typename OutT>
__global__ __launch_bounds__(256, 2) void gemm_bt_kernel(
    const bf16* __restrict__ A, const bf16* __restrict__ B, OutT* __restrict__ C,
    int M, int N, int K) {
  __shared__ __align__(16) bf16 As[128 * 64];
  __shared__ __align__(16) bf16 Bs[128 * 64];

  int nwg = gridDim.x * gridDim.y;
  int bid = blockIdx.y * gridDim.x + blockIdx.x;
  int cpx = nwg >> 3;
  int swz = (bid & 7) * cpx + (bid >> 3);
  int bx = swz % gridDim.x, by = swz / gridDim.x;
  const int n0 = bx * 128, m0 = by * 128;

  const int t = threadIdx.x;
  const int lane = t & 63, w = t >> 6;
  const int wr = w >> 1, wc = w & 1;
  const int lg = lane >> 4, lm = lane & 15;
  f32x4 acc[4][4] = {};

  for (int k0 = 0; k0 < K; k0 += 64) {
    __syncthreads();
#pragma unroll
    for (int i = 0; i < 4; ++i) {
      int c = i * 256 + t;
      int r = c >> 3, jl = c & 7;
      int jg = jl ^ (r & 7);
      const bf16* srcA = A + (long)(m0 + r) * K + k0 + jg * 8;
      __builtin_amdgcn_global_load_lds((const __attribute__((address_space(1))) void*)srcA,
                                       (__attribute__((address_space(3))) void*)(As + c * 8), 16, 0, 0);
      const bf16* srcB = B + (long)(n0 + r) * K + k0 + jg * 8;
      __builtin_amdgcn_global_load_lds((const __attribute__((address_space(1))) void*)srcB,
                                       (__attribute__((address_space(3))) void*)(Bs + c * 8), 16, 0, 0);
    }
    __syncthreads();
#pragma unroll
    for (int ks = 0; ks < 2; ++ks) {
      bf16x8 a[4], b[4];
#pragma unroll
      for (int m = 0; m < 4; ++m) {
        int r = wr * 64 + m * 16 + lm;
        int j = ks * 4 + lg;
        a[m] = *reinterpret_cast<const bf16x8*>(As + r * 64 + ((j ^ (r & 7)) << 3));
      }
#pragma unroll
      for (int n = 0; n < 4; ++n) {
        int r = wc * 64 + n * 16 + lm;
        int j = ks * 4 + lg;
        b[n] = *reinterpret_cast<const bf16x8*>(Bs + r * 64 + ((j ^ (r & 7)) << 3));
      }
#pragma unroll
      for (int m = 0; m < 4; ++m)
#pragma unroll
        for (int n = 0; n < 4; ++n)
          acc[m][n] = __builtin_amdgcn_mfma_f32_16x16x32_bf16(a[m], b[n], acc[m][n], 0, 0, 0);
    }
  }
#pragma unroll
  for (int m = 0; m < 4; ++m) {
    int row = m0 + wr * 64 + m * 16 + lg * 4;
#pragma unroll
    for (int n = 0; n < 4; ++n) {
      int col = n0 + wc * 64 + n * 16 + lm;
#pragma unroll
      for (int r = 0; r < 4; ++r) {
        float v = acc[m][n][r];
        if constexpr (sizeof(OutT) == 4) C[(long)(row + r) * N + col] = v;
        else                             C[(long)(row + r) * N + col] = (bf16)v;
      }
    }
  }
}

// ---------------- GQA causal flash attention, v2 ----------------
// 4 waves x 16 q-rows = QBLK 64; KVBLK=64; triangle-paired q-tiles for balance.
// K: global_load_lds + 16-chunk XOR swizzle (linear LDS). V: reg transpose, b64 writes.
__global__ __launch_bounds__(256, 2) void attn_kernel(const bf16* __restrict__ qkv,
                                                      bf16* __restrict__ out) {
  __shared__ __align__(16) bf16 Ks[64 * 128];
  __shared__ __align__(16) bf16 Vt[128 * PADV];
  __shared__ __align__(16) bf16 Pw[4 * 16 * PADP];

  const int h = blockIdx.y;
  const int kvh = h >> 2;               // GROUPS = 4
  const int t = threadIdx.x, lane = t & 63, w = t >> 6;
  const int lg = lane >> 4, lm = lane & 15;
  bf16* pw = Pw + w * 16 * PADP;

  const int dchunk = t >> 4, kv4 = t & 15;   // V-staging assignment

#pragma unroll 1
  for (int phase = 0; phase < 2; ++phase) {
    const int qt = (phase == 0) ? (int)blockIdx.x : 31 - (int)blockIdx.x;
    const int q0 = qt * 64;

    // Q fragments: A-frag layout Q[row=lm][k=ks*32+lg*8+j]
    const long qrow = q0 + w * 16 + lm;
    bf16x8 qf[4];
#pragma unroll
    for (int ks = 0; ks < 4; ++ks)
      qf[ks] = *reinterpret_cast<const bf16x8*>(qkv + qrow * QKV_N + h * HD + ks * 32 + lg * 8);

    f32x4 o[8];
#pragma unroll
    for (int i = 0; i < 8; ++i) o[i] = f32x4{0.f, 0.f, 0.f, 0.f};
    float mrow[4] = {-1e30f, -1e30f, -1e30f, -1e30f};
    float lrow[4] = {0.f, 0.f, 0.f, 0.f};

    const int nst = qt + 1;
    for (int st = 0; st < nst; ++st) {
      const int kv0 = st * 64;
      __syncthreads();
      // ---- stage K [64][128] linear, source chunk-XOR-swizzled (rule #21) ----
#pragma unroll
      for (int i = 0; i < 4; ++i) {
        int c = i * 256 + t;
        int r = c >> 4, jl = c & 15;
        int jg = jl ^ (r & 15);
        const bf16* src = qkv + (long)(kv0 + r) * QKV_N + K_COL + kvh * HD + jg * 8;
        __builtin_amdgcn_global_load_lds((const __attribute__((address_space(1))) void*)src,
                                         (__attribute__((address_space(3))) void*)(Ks + c * 8), 16, 0, 0);
      }
      // ---- stage V transposed: thread owns (kv4*4..+3, dchunk*8..+7) ----
      {
        const bf16* vsrc = qkv + (long)(kv0 + kv4 * 4) * QKV_N + V_COL + kvh * HD + dchunk * 8;
        bf16x8 v0 = *reinterpret_cast<const bf16x8*>(vsrc);
        bf16x8 v1 = *reinterpret_cast<const bf16x8*>(vsrc + QKV_N);
        bf16x8 v2 = *reinterpret_cast<const bf16x8*>(vsrc + 2 * QKV_N);
        bf16x8 v3 = *reinterpret_cast<const bf16x8*>(vsrc + 3 * QKV_N);
#pragma unroll
        for (int e = 0; e < 8; ++e) {
          bf16x4 pk; pk[0] = v0[e]; pk[1] = v1[e]; pk[2] = v2[e]; pk[3] = v3[e];
          *reinterpret_cast<bf16x4*>(Vt + (dchunk * 8 + e) * PADV + kv4 * 4) = pk;
        }
      }
      __syncthreads();

      // ---- S = Q @ K^T : 4 col-blocks of 16 ----
      f32x4 s[4];
#pragma unroll
      for (int cb = 0; cb < 4; ++cb) s[cb] = f32x4{0.f, 0.f, 0.f, 0.f};
#pragma unroll
      for (int ks = 0; ks < 4; ++ks) {
#pragma unroll
        for (int cb = 0; cb < 4; ++cb) {
          bf16x8 kf = *reinterpret_cast<const bf16x8*>(
              Ks + (cb * 16 + lm) * 128 + (((ks * 4 + lg) ^ lm) << 3));
          s[cb] = __builtin_amdgcn_mfma_f32_16x16x32_bf16(qf[ks], kf, s[cb], 0, 0, 0);
        }
      }

      // ---- online softmax (log2 domain) ----
      const float SC = 0.12751742f;     // (1/sqrt(128)) * log2(e)
      float sl[4][4];
#pragma unroll
      for (int cb = 0; cb < 4; ++cb)
#pragma unroll
        for (int r = 0; r < 4; ++r) sl[cb][r] = s[cb][r] * SC;
      if (st == qt) {                   // diagonal tile: causal mask
#pragma unroll
        for (int cb = 0; cb < 4; ++cb)
#pragma unroll
          for (int r = 0; r < 4; ++r)
            if (cb * 16 + lm > w * 16 + lg * 4 + r) sl[cb][r] = -1e30f;
      }
      float tm[4];
#pragma unroll
      for (int r = 0; r < 4; ++r)
        tm[r] = fmaxf(fmaxf(sl[0][r], sl[1][r]), fmaxf(sl[2][r], sl[3][r]));
#pragma unroll
      for (int off = 1; off < 16; off <<= 1)
#pragma unroll
        for (int r = 0; r < 4; ++r) tm[r] = fmaxf(tm[r], __shfl_xor(tm[r], off));
      float alpha[4], psum[4], p[4][4];
#pragma unroll
      for (int r = 0; r < 4; ++r) {
        float mnew = fmaxf(mrow[r], tm[r]);
        alpha[r] = exp2f(mrow[r] - mnew);
        mrow[r] = mnew;
#pragma unroll
        for (int cb = 0; cb < 4; ++cb) p[cb][r] = exp2f(sl[cb][r] - mnew);
        psum[r] = (p[0][r] + p[1][r]) + (p[2][r] + p[3][r]);
      }
#pragma unroll
      for (int off = 1; off < 16; off <<= 1)
#pragma unroll
        for (int r = 0; r < 4; ++r) psum[r] += __shfl_xor(psum[r], off);
#pragma unroll
      for (int r = 0; r < 4; ++r) lrow[r] = lrow[r] * alpha[r] + psum[r];
#pragma unroll
      for (int i = 0; i < 8; ++i)
#pragma unroll
        for (int r = 0; r < 4; ++r) o[i][r] *= alpha[r];

      // ---- P -> LDS (bf16), per-wave region; C-layout rows -> A-layout reads ----
#pragma unroll
      for (int cb = 0; cb < 4; ++cb)
#pragma unroll
        for (int r = 0; r < 4; ++r)
          pw[(lg * 4 + r) * PADP + cb * 16 + lm] = (bf16)p[cb][r];

      // ---- PV: o[db] += P[16x64] @ V[64x(db block)] ----
      bf16x8 pa0 = *reinterpret_cast<const bf16x8*>(pw + lm * PADP + lg * 8);
      bf16x8 pa1 = *reinterpret_cast<const bf16x8*>(pw + lm * PADP + 32 + lg * 8);
#pragma unroll
      for (int db = 0; db < 8; ++db) {
        bf16x8 vf0 = *reinterpret_cast<const bf16x8*>(Vt + (db * 16 + lm) * PADV + lg * 8);
        bf16x8 vf1 = *reinterpret_cast<const bf16x8*>(Vt + (db * 16 + lm) * PADV + 32 + lg * 8);
        o[db] = __builtin_amdgcn_mfma_f32_16x16x32_bf16(pa0, vf0, o[db], 0, 0, 0);
        o[db] = __builtin_amdgcn_mfma_f32_16x16x32_bf16(pa1, vf1, o[db], 0, 0, 0);
      }
    }

    // ---- epilogue: normalize + store bf16 [S][4096] ----
#pragma unroll
    for (int r = 0; r < 4; ++r) {
      float inv = 1.0f / lrow[r];
      long row = q0 + w * 16 + lg * 4 + r;
#pragma unroll
      for (int db = 0; db < 8; ++db)
        out[row * HID_DIM + h * HD + db * 16 + lm] = (bf16)(o[db][r] * inv);
    }
  }
}

extern "C" void kernel_launch(void* const* d_in, const int* in_sizes, int n_in,
                              void* d_out, int out_size, void* d_ws, size_t ws_size,
                              hipStream_t stream) {
  const float* hs = (const float*)d_in[0];
  const float* Wq = (const float*)d_in[1];
  const float* Wk = (const float*)d_in[2];
  const float* Wv = (const float*)d_in[3];
  const float* Wo = (const float*)d_in[4];
  float* out = (float*)d_out;
  char* ws = (char*)d_ws;

  bf16*  hsb   = (bf16*)(ws);                    // 2048x4096 bf16
  bf16*  wqkvb = (bf16*)(ws + 16777216);         // 6144x4096 bf16
  bf16*  wob   = (bf16*)(ws + 67108864);         // 4096x4096 bf16
  bf16*  qkv   = (bf16*)(ws + 100663296);        // 2048x6144 bf16
  bf16*  attn  = (bf16*)(ws + 125829120);        // 2048x4096 bf16
  float* cost  = (float*)(ws + 142606336);       // 2048x64 f32
  float* sint  = (float*)(ws + 143130624);       // 2048x64 f32

  cvt_f32_bf16_kernel<<<8192,  256, 0, stream>>>(hs, hsb, 2097152);
  cvt_f32_bf16_kernel<<<16384, 256, 0, stream>>>(Wq, wqkvb, 4194304);
  cvt_f32_bf16_kernel<<<4096,  256, 0, stream>>>(Wk, wqkvb + (long)4096 * 4096, 1048576);
  cvt_f32_bf16_kernel<<<4096,  256, 0, stream>>>(Wv, wqkvb + (long)5120 * 4096, 1048576);
  cvt_f32_bf16_kernel<<<16384, 256, 0, stream>>>(Wo, wob, 4194304);
  rope_table_kernel<<<512, 256, 0, stream>>>(cost, sint);
  gemm_bt_kernel<bf16><<<dim3(48, 16), 256, 0, stream>>>(hsb, wqkvb, qkv, 2048, 6144, 4096);
  rope_apply_kernel<<<20480, 256, 0, stream>>>(qkv, cost, sint);
  attn_kernel<<<dim3(16, 32), 256, 0, stream>>>(qkv, attn);
  gemm_bt_kernel<float><<<dim3(32, 16), 256, 0, stream>>>(attn, wob, out, 2048, 4096, 4096);
}

// Round 3
// 374.061 us; speedup vs baseline: 1.8105x; 1.0239x over previous
//
#include <hip/hip_runtime.h>

typedef __bf16 bf16;
typedef __bf16 bf16x4 __attribute__((ext_vector_type(4)));
typedef __bf16 bf16x8 __attribute__((ext_vector_type(8)));
typedef float f32x4 __attribute__((ext_vector_type(4)));

#define S_LEN 2048
#define HID_DIM 4096
#define NH 32
#define NKV 8
#define HD 128
#define QKV_N 6144   // 4096 Q + 1024 K + 1024 V
#define K_COL 4096
#define V_COL 5120
#define PADV 76
#define PADP 68

// ---------------- fp32 -> bf16 conversion (vectorized) ----------------
__global__ void cvt_f32_bf16_kernel(const float* __restrict__ in, bf16* __restrict__ out, int n4) {
  int i = blockIdx.x * blockDim.x + threadIdx.x;
  if (i >= n4) return;
  float4 v = reinterpret_cast<const float4*>(in)[i];
  bf16x4 o;
  o[0] = (bf16)v.x; o[1] = (bf16)v.y; o[2] = (bf16)v.z; o[3] = (bf16)v.w;
  reinterpret_cast<bf16x4*>(out)[i] = o;
}

// ---------------- RoPE tables: cos/sin [S][64] fp32 ----------------
__global__ void rope_table_kernel(float* __restrict__ cost, float* __restrict__ sint) {
  int i = blockIdx.x * blockDim.x + threadIdx.x;   // 2048*64
  int s = i >> 6, d = i & 63;
  float inv = expf(-0.14391156831212787f * (float)d);   // 10000^(-d/64)
  float ang = (float)s * inv;
  cost[i] = cosf(ang);
  sint[i] = sinf(ang);
}

// ---------------- RoPE apply in-place, vectorized bf16x8 ----------------
__global__ void rope_apply_kernel(bf16* __restrict__ qkv, const float* __restrict__ cost,
                                  const float* __restrict__ sint) {
  int idx = blockIdx.x * blockDim.x + threadIdx.x;  // 2048 rows * 320 chunks
  int s = idx / 320;
  int c = idx - s * 320;
  int g = c >> 3, dc = (c & 7) * 8;      // head-slot 0..39, d-chunk of 8 within 0..63
  long base = (long)s * QKV_N + g * 128 + dc;
  bf16x8 x1 = *reinterpret_cast<const bf16x8*>(qkv + base);
  bf16x8 x2 = *reinterpret_cast<const bf16x8*>(qkv + base + 64);
  const float* cp = cost + (s << 6) + dc;
  const float* sp = sint + (s << 6) + dc;
  float4 ca = *reinterpret_cast<const float4*>(cp);
  float4 cb = *reinterpret_cast<const float4*>(cp + 4);
  float4 sa = *reinterpret_cast<const float4*>(sp);
  float4 sb = *reinterpret_cast<const float4*>(sp + 4);
  float co[8] = {ca.x, ca.y, ca.z, ca.w, cb.x, cb.y, cb.z, cb.w};
  float sn[8] = {sa.x, sa.y, sa.z, sa.w, sb.x, sb.y, sb.z, sb.w};
  bf16x8 y1, y2;
#pragma unroll
  for (int e = 0; e < 8; ++e) {
    float a = (float)x1[e], b = (float)x2[e];
    y1[e] = (bf16)(a * co[e] - b * sn[e]);
    y2[e] = (bf16)(b * co[e] + a * sn[e]);
  }
  *reinterpret_cast<bf16x8*>(qkv + base)      = y1;
  *reinterpret_cast<bf16x8*>(qkv + base + 64) = y2;
}

// ---------------- bf16 GEMM, C[M,N] = A[M,K] @ B[N,K]^T (m97 structure) ----------------
template<typename OutT>
__global__ __launch_bounds__(256, 2) void gemm_bt_kernel(
    const bf16* __restrict__ A, const bf16* __restrict__ B, OutT* __restrict__ C,
    int M, int N, int K) {
  __shared__ __align__(16) bf16 As[128 * 64];
  __shared__ __align__(16) bf16 Bs[128 * 64];

  int nwg = gridDim.x * gridDim.y;
  int bid = blockIdx.y * gridDim.x + blockIdx.x;
  int cpx = nwg >> 3;
  int swz = (bid & 7) * cpx + (bid >> 3);
  int bx = swz % gridDim.x, by = swz / gridDim.x;
  const int n0 = bx * 128, m0 = by * 128;

  const int t = threadIdx.x;
  const int lane = t & 63, w = t >> 6;
  const int wr = w >> 1, wc = w & 1;
  const int lg = lane >> 4, lm = lane & 15;
  f32x4 acc[4][4] = {};

  for (int k0 = 0; k0 < K; k0 += 64) {
    __syncthreads();
#pragma unroll
    for (int i = 0; i < 4; ++i) {
      int c = i * 256 + t;
      int r = c >> 3, jl = c & 7;
      int jg = jl ^ (r & 7);
      const bf16* srcA = A + (long)(m0 + r) * K + k0 + jg * 8;
      __builtin_amdgcn_global_load_lds((const __attribute__((address_space(1))) void*)srcA,
                                       (__attribute__((address_space(3))) void*)(As + c * 8), 16, 0, 0);
      const bf16* srcB = B + (long)(n0 + r) * K + k0 + jg * 8;
      __builtin_amdgcn_global_load_lds((const __attribute__((address_space(1))) void*)srcB,
                                       (__attribute__((address_space(3))) void*)(Bs + c * 8), 16, 0, 0);
    }
    __syncthreads();
#pragma unroll
    for (int ks = 0; ks < 2; ++ks) {
      bf16x8 a[4], b[4];
#pragma unroll
      for (int m = 0; m < 4; ++m) {
        int r = wr * 64 + m * 16 + lm;
        int j = ks * 4 + lg;
        a[m] = *reinterpret_cast<const bf16x8*>(As + r * 64 + ((j ^ (r & 7)) << 3));
      }
#pragma unroll
      for (int n = 0; n < 4; ++n) {
        int r = wc * 64 + n * 16 + lm;
        int j = ks * 4 + lg;
        b[n] = *reinterpret_cast<const bf16x8*>(Bs + r * 64 + ((j ^ (r & 7)) << 3));
      }
#pragma unroll
      for (int m = 0; m < 4; ++m)
#pragma unroll
        for (int n = 0; n < 4; ++n)
          acc[m][n] = __builtin_amdgcn_mfma_f32_16x16x32_bf16(a[m], b[n], acc[m][n], 0, 0, 0);
    }
  }
#pragma unroll
  for (int m = 0; m < 4; ++m) {
    int row = m0 + wr * 64 + m * 16 + lg * 4;
#pragma unroll
    for (int n = 0; n < 4; ++n) {
      int col = n0 + wc * 64 + n * 16 + lm;
#pragma unroll
      for (int r = 0; r < 4; ++r) {
        float v = acc[m][n][r];
        if constexpr (sizeof(OutT) == 4) C[(long)(row + r) * N + col] = v;
        else                             C[(long)(row + r) * N + col] = (bf16)v;
      }
    }
  }
}

// ---------------- GQA causal flash attention, v3 ----------------
// 4 waves x 16 q-rows; KVBLK=64; triangle pairing; DOUBLE-BUFFERED K/V with
// async-stage split (issue-early/write-late), one barrier per step; setprio
// around MFMA clusters; defer-max rescale (THR=8 log2-units).
__global__ __launch_bounds__(256, 2) void attn_kernel(const bf16* __restrict__ qkv,
                                                      bf16* __restrict__ out) {
  __shared__ __align__(16) bf16 Ks[2][64 * 128];
  __shared__ __align__(16) bf16 Vt[2][128 * PADV];
  __shared__ __align__(16) bf16 Pw[4 * 16 * PADP];

  const int h = blockIdx.y;
  const int kvh = h >> 2;               // GROUPS = 4
  const int t = threadIdx.x, lane = t & 63, w = t >> 6;
  const int lg = lane >> 4, lm = lane & 15;
  bf16* pw = Pw + w * 16 * PADP;
  const int dchunk = t >> 4, kv4 = t & 15;     // V-staging assignment
  const bf16* kbase = qkv + K_COL + kvh * HD;
  const bf16* vbase = qkv + V_COL + kvh * HD;

#pragma unroll 1
  for (int phase = 0; phase < 2; ++phase) {
    const int qt = (phase == 0) ? (int)blockIdx.x : 31 - (int)blockIdx.x;
    const int q0 = qt * 64;
    const int nst = qt + 1;

    // Q fragments: A-frag layout Q[row=lm][k=ks*32+lg*8+j]
    const long qrow = q0 + w * 16 + lm;
    bf16x8 qf[4];
#pragma unroll
    for (int ks = 0; ks < 4; ++ks)
      qf[ks] = *reinterpret_cast<const bf16x8*>(qkv + qrow * QKV_N + h * HD + ks * 32 + lg * 8);

    f32x4 o[8];
#pragma unroll
    for (int i = 0; i < 8; ++i) o[i] = f32x4{0.f, 0.f, 0.f, 0.f};
    float mrow[4] = {-1e30f, -1e30f, -1e30f, -1e30f};
    float lrow[4] = {0.f, 0.f, 0.f, 0.f};

    // ---- prologue: stage st=0 into buffer 0 ----
    {
#pragma unroll
      for (int i = 0; i < 4; ++i) {
        int c = i * 256 + t;
        int r = c >> 4, jl = c & 15;
        int jg = jl ^ (r & 15);
        const bf16* src = kbase + (long)r * QKV_N + jg * 8;
        __builtin_amdgcn_global_load_lds((const __attribute__((address_space(1))) void*)src,
                                         (__attribute__((address_space(3))) void*)(Ks[0] + c * 8), 16, 0, 0);
      }
      const bf16* vs = vbase + (long)(kv4 * 4) * QKV_N + dchunk * 8;
      bf16x8 a0 = *reinterpret_cast<const bf16x8*>(vs);
      bf16x8 a1 = *reinterpret_cast<const bf16x8*>(vs + QKV_N);
      bf16x8 a2 = *reinterpret_cast<const bf16x8*>(vs + 2 * QKV_N);
      bf16x8 a3 = *reinterpret_cast<const bf16x8*>(vs + 3 * QKV_N);
#pragma unroll
      for (int e = 0; e < 8; ++e) {
        bf16x4 pk; pk[0] = a0[e]; pk[1] = a1[e]; pk[2] = a2[e]; pk[3] = a3[e];
        *reinterpret_cast<bf16x4*>(Vt[0] + (dchunk * 8 + e) * PADV + kv4 * 4) = pk;
      }
      __syncthreads();   // drains global_load_lds vmcnt
    }

    for (int st = 0; st < nst; ++st) {
      const int cur = st & 1, nxt = cur ^ 1;
      const bool pf = (st + 1 < nst);

      // ---- issue next-step staging EARLY (T14): K -> Ks[nxt], V -> regs ----
      bf16x8 a0, a1, a2, a3;
      if (pf) {
        const long kv0n = (long)(st + 1) * 64;
#pragma unroll
        for (int i = 0; i < 4; ++i) {
          int c = i * 256 + t;
          int r = c >> 4, jl = c & 15;
          int jg = jl ^ (r & 15);
          const bf16* src = kbase + (kv0n + r) * QKV_N + jg * 8;
          __builtin_amdgcn_global_load_lds((const __attribute__((address_space(1))) void*)src,
                                           (__attribute__((address_space(3))) void*)(Ks[nxt] + c * 8), 16, 0, 0);
        }
        const bf16* vs = vbase + (kv0n + kv4 * 4) * QKV_N + dchunk * 8;
        a0 = *reinterpret_cast<const bf16x8*>(vs);
        a1 = *reinterpret_cast<const bf16x8*>(vs + QKV_N);
        a2 = *reinterpret_cast<const bf16x8*>(vs + 2 * QKV_N);
        a3 = *reinterpret_cast<const bf16x8*>(vs + 3 * QKV_N);
      }

      // ---- S = Q @ K^T : 4 col-blocks of 16 ----
      f32x4 s[4];
#pragma unroll
      for (int cb = 0; cb < 4; ++cb) s[cb] = f32x4{0.f, 0.f, 0.f, 0.f};
      __builtin_amdgcn_s_setprio(1);
#pragma unroll
      for (int ks = 0; ks < 4; ++ks) {
#pragma unroll
        for (int cb = 0; cb < 4; ++cb) {
          bf16x8 kf = *reinterpret_cast<const bf16x8*>(
              Ks[cur] + (cb * 16 + lm) * 128 + (((ks * 4 + lg) ^ lm) << 3));
          s[cb] = __builtin_amdgcn_mfma_f32_16x16x32_bf16(qf[ks], kf, s[cb], 0, 0, 0);
        }
      }
      __builtin_amdgcn_s_setprio(0);

      // ---- online softmax (log2 domain) ----
      const float SC = 0.12751742f;     // (1/sqrt(128)) * log2(e)
      float sl[4][4];
#pragma unroll
      for (int cb = 0; cb < 4; ++cb)
#pragma unroll
        for (int r = 0; r < 4; ++r) sl[cb][r] = s[cb][r] * SC;
      if (st == qt) {                   // diagonal tile: causal mask
#pragma unroll
        for (int cb = 0; cb < 4; ++cb)
#pragma unroll
          for (int r = 0; r < 4; ++r)
            if (cb * 16 + lm > w * 16 + lg * 4 + r) sl[cb][r] = -1e30f;
      }
      float tm[4];
#pragma unroll
      for (int r = 0; r < 4; ++r)
        tm[r] = fmaxf(fmaxf(sl[0][r], sl[1][r]), fmaxf(sl[2][r], sl[3][r]));
#pragma unroll
      for (int off = 1; off < 16; off <<= 1)
#pragma unroll
        for (int r = 0; r < 4; ++r) tm[r] = fmaxf(tm[r], __shfl_xor(tm[r], off));

      // defer-max (T13): only rescale when some row max grew past threshold
      bool grow = (tm[0] > mrow[0] + 8.f) || (tm[1] > mrow[1] + 8.f) ||
                  (tm[2] > mrow[2] + 8.f) || (tm[3] > mrow[3] + 8.f);
      if (__any(grow)) {
        float alpha[4];
#pragma unroll
        for (int r = 0; r < 4; ++r) {
          float mnew = fmaxf(mrow[r], tm[r]);
          alpha[r] = exp2f(mrow[r] - mnew);
          mrow[r] = mnew;
          lrow[r] *= alpha[r];
        }
#pragma unroll
        for (int i = 0; i < 8; ++i)
#pragma unroll
          for (int r = 0; r < 4; ++r) o[i][r] *= alpha[r];
      }
      float p[4][4], psum[4];
#pragma unroll
      for (int r = 0; r < 4; ++r) {
#pragma unroll
        for (int cb = 0; cb < 4; ++cb) p[cb][r] = exp2f(sl[cb][r] - mrow[r]);
        psum[r] = (p[0][r] + p[1][r]) + (p[2][r] + p[3][r]);
      }
#pragma unroll
      for (int off = 1; off < 16; off <<= 1)
#pragma unroll
        for (int r = 0; r < 4; ++r) psum[r] += __shfl_xor(psum[r], off);
#pragma unroll
      for (int r = 0; r < 4; ++r) lrow[r] += psum[r];

      // ---- P -> LDS (bf16), per-wave region ----
#pragma unroll
      for (int cb = 0; cb < 4; ++cb)
#pragma unroll
        for (int r = 0; r < 4; ++r)
          pw[(lg * 4 + r) * PADP + cb * 16 + lm] = (bf16)p[cb][r];

      // ---- PV: o[db] += P[16x64] @ V[64x(db block)] ----
      bf16x8 pa0 = *reinterpret_cast<const bf16x8*>(pw + lm * PADP + lg * 8);
      bf16x8 pa1 = *reinterpret_cast<const bf16x8*>(pw + lm * PADP + 32 + lg * 8);
      __builtin_amdgcn_s_setprio(1);
#pragma unroll
      for (int db = 0; db < 8; ++db) {
        bf16x8 vf0 = *reinterpret_cast<const bf16x8*>(Vt[cur] + (db * 16 + lm) * PADV + lg * 8);
        bf16x8 vf1 = *reinterpret_cast<const bf16x8*>(Vt[cur] + (db * 16 + lm) * PADV + 32 + lg * 8);
        o[db] = __builtin_amdgcn_mfma_f32_16x16x32_bf16(pa0, vf0, o[db], 0, 0, 0);
        o[db] = __builtin_amdgcn_mfma_f32_16x16x32_bf16(pa1, vf1, o[db], 0, 0, 0);
      }
      __builtin_amdgcn_s_setprio(0);

      // ---- write-late: V regs -> Vt[nxt] ----
      if (pf) {
#pragma unroll
        for (int e = 0; e < 8; ++e) {
          bf16x4 pk; pk[0] = a0[e]; pk[1] = a1[e]; pk[2] = a2[e]; pk[3] = a3[e];
          *reinterpret_cast<bf16x4*>(Vt[nxt] + (dchunk * 8 + e) * PADV + kv4 * 4) = pk;
        }
      }
      __syncthreads();   // drains K gload_lds; publishes Vt[nxt]
    }

    // ---- epilogue: normalize + store bf16 [S][4096] ----
#pragma unroll
    for (int r = 0; r < 4; ++r) {
      float inv = 1.0f / lrow[r];
      long row = q0 + w * 16 + lg * 4 + r;
#pragma unroll
      for (int db = 0; db < 8; ++db)
        out[row * HID_DIM + h * HD + db * 16 + lm] = (bf16)(o[db][r] * inv);
    }
  }
}

extern "C" void kernel_launch(void* const* d_in, const int* in_sizes, int n_in,
                              void* d_out, int out_size, void* d_ws, size_t ws_size,
                              hipStream_t stream) {
  const float* hs = (const float*)d_in[0];
  const float* Wq = (const float*)d_in[1];
  const float* Wk = (const float*)d_in[2];
  const float* Wv = (const float*)d_in[3];
  const float* Wo = (const float*)d_in[4];
  float* out = (float*)d_out;
  char* ws = (char*)d_ws;

  bf16*  hsb   = (bf16*)(ws);                    // 2048x4096 bf16
  bf16*  wqkvb = (bf16*)(ws + 16777216);         // 6144x4096 bf16
  bf16*  wob   = (bf16*)(ws + 67108864);         // 4096x4096 bf16
  bf16*  qkv   = (bf16*)(ws + 100663296);        // 2048x6144 bf16
  bf16*  attn  = (bf16*)(ws + 125829120);        // 2048x4096 bf16
  float* cost  = (float*)(ws + 142606336);       // 2048x64 f32
  float* sint  = (float*)(ws + 143130624);       // 2048x64 f32

  cvt_f32_bf16_kernel<<<8192,  256, 0, stream>>>(hs, hsb, 2097152);
  cvt_f32_bf16_kernel<<<16384, 256, 0, stream>>>(Wq, wqkvb, 4194304);
  cvt_f32_bf16_kernel<<<4096,  256, 0, stream>>>(Wk, wqkvb + (long)4096 * 4096, 1048576);
  cvt_f32_bf16_kernel<<<4096,  256, 0, stream>>>(Wv, wqkvb + (long)5120 * 4096, 1048576);
  cvt_f32_bf16_kernel<<<16384, 256, 0, stream>>>(Wo, wob, 4194304);
  rope_table_kernel<<<512, 256, 0, stream>>>(cost, sint);
  gemm_bt_kernel<bf16><<<dim3(48, 16), 256, 0, stream>>>(hsb, wqkvb, qkv, 2048, 6144, 4096);
  rope_apply_kernel<<<2560, 256, 0, stream>>>(qkv, cost, sint);
  attn_kernel<<<dim3(16, 32), 256, 0, stream>>>(qkv, attn);
  gemm_bt_kernel<float><<<dim3(32, 16), 256, 0, stream>>>(attn, wob, out, 2048, 4096, 4096);
}

// Round 4
// 369.677 us; speedup vs baseline: 1.8319x; 1.0119x over previous
//
#include <hip/hip_runtime.h>

typedef __bf16 bf16;
typedef __bf16 bf16x4 __attribute__((ext_vector_type(4)));
typedef __bf16 bf16x8 __attribute__((ext_vector_type(8)));
typedef float f32x4 __attribute__((ext_vector_type(4)));

#define S_LEN 2048
#define HID_DIM 4096
#define NH 32
#define NKV 8
#define HD 128
#define QKV_N 6144   // 4096 Q + 1024 K + 1024 V
#define K_COL 4096
#define V_COL 5120
#define PADV 76
#define PADP 68

// ---------------- fp32 -> bf16 conversion (vectorized) ----------------
__global__ void cvt_f32_bf16_kernel(const float* __restrict__ in, bf16* __restrict__ out, int n4) {
  int i = blockIdx.x * blockDim.x + threadIdx.x;
  if (i >= n4) return;
  float4 v = reinterpret_cast<const float4*>(in)[i];
  bf16x4 o;
  o[0] = (bf16)v.x; o[1] = (bf16)v.y; o[2] = (bf16)v.z; o[3] = (bf16)v.w;
  reinterpret_cast<bf16x4*>(out)[i] = o;
}

// ---------------- RoPE tables: cos/sin [S][64] fp32 ----------------
__global__ void rope_table_kernel(float* __restrict__ cost, float* __restrict__ sint) {
  int i = blockIdx.x * blockDim.x + threadIdx.x;   // 2048*64
  int s = i >> 6, d = i & 63;
  float inv = expf(-0.14391156831212787f * (float)d);   // 10000^(-d/64)
  float ang = (float)s * inv;
  cost[i] = cosf(ang);
  sint[i] = sinf(ang);
}

// ---------------- RoPE apply in-place, vectorized bf16x8 ----------------
__global__ void rope_apply_kernel(bf16* __restrict__ qkv, const float* __restrict__ cost,
                                  const float* __restrict__ sint) {
  int idx = blockIdx.x * blockDim.x + threadIdx.x;  // 2048 rows * 320 chunks
  int s = idx / 320;
  int c = idx - s * 320;
  int g = c >> 3, dc = (c & 7) * 8;      // head-slot 0..39, d-chunk of 8 within 0..63
  long base = (long)s * QKV_N + g * 128 + dc;
  bf16x8 x1 = *reinterpret_cast<const bf16x8*>(qkv + base);
  bf16x8 x2 = *reinterpret_cast<const bf16x8*>(qkv + base + 64);
  const float* cp = cost + (s << 6) + dc;
  const float* sp = sint + (s << 6) + dc;
  float4 ca = *reinterpret_cast<const float4*>(cp);
  float4 cb = *reinterpret_cast<const float4*>(cp + 4);
  float4 sa = *reinterpret_cast<const float4*>(sp);
  float4 sb = *reinterpret_cast<const float4*>(sp + 4);
  float co[8] = {ca.x, ca.y, ca.z, ca.w, cb.x, cb.y, cb.z, cb.w};
  float sn[8] = {sa.x, sa.y, sa.z, sa.w, sb.x, sb.y, sb.z, sb.w};
  bf16x8 y1, y2;
#pragma unroll
  for (int e = 0; e < 8; ++e) {
    float a = (float)x1[e], b = (float)x2[e];
    y1[e] = (bf16)(a * co[e] - b * sn[e]);
    y2[e] = (bf16)(b * co[e] + a * sn[e]);
  }
  *reinterpret_cast<bf16x8*>(qkv + base)      = y1;
  *reinterpret_cast<bf16x8*>(qkv + base + 64) = y2;
}

// ---------------- bf16 GEMM, C[M,N] = A[M,K] @ B[N,K]^T (m97 structure) ----------------
template<typename OutT>
__global__ __launch_bounds__(256, 2) void gemm_bt_kernel(
    const bf16* __restrict__ A, const bf16* __restrict__ B, OutT* __restrict__ C,
    int M, int N, int K) {
  __shared__ __align__(16) bf16 As[128 * 64];
  __shared__ __align__(16) bf16 Bs[128 * 64];

  int nwg = gridDim.x * gridDim.y;
  int bid = blockIdx.y * gridDim.x + blockIdx.x;
  int cpx = nwg >> 3;
  int swz = (bid & 7) * cpx + (bid >> 3);
  int bx = swz % gridDim.x, by = swz / gridDim.x;
  const int n0 = bx * 128, m0 = by * 128;

  const int t = threadIdx.x;
  const int lane = t & 63, w = t >> 6;
  const int wr = w >> 1, wc = w & 1;
  const int lg = lane >> 4, lm = lane & 15;
  f32x4 acc[4][4] = {};

  for (int k0 = 0; k0 < K; k0 += 64) {
    __syncthreads();
#pragma unroll
    for (int i = 0; i < 4; ++i) {
      int c = i * 256 + t;
      int r = c >> 3, jl = c & 7;
      int jg = jl ^ (r & 7);
      const bf16* srcA = A + (long)(m0 + r) * K + k0 + jg * 8;
      __builtin_amdgcn_global_load_lds((const __attribute__((address_space(1))) void*)srcA,
                                       (__attribute__((address_space(3))) void*)(As + c * 8), 16, 0, 0);
      const bf16* srcB = B + (long)(n0 + r) * K + k0 + jg * 8;
      __builtin_amdgcn_global_load_lds((const __attribute__((address_space(1))) void*)srcB,
                                       (__attribute__((address_space(3))) void*)(Bs + c * 8), 16, 0, 0);
    }
    __syncthreads();
#pragma unroll
    for (int ks = 0; ks < 2; ++ks) {
      bf16x8 a[4], b[4];
#pragma unroll
      for (int m = 0; m < 4; ++m) {
        int r = wr * 64 + m * 16 + lm;
        int j = ks * 4 + lg;
        a[m] = *reinterpret_cast<const bf16x8*>(As + r * 64 + ((j ^ (r & 7)) << 3));
      }
#pragma unroll
      for (int n = 0; n < 4; ++n) {
        int r = wc * 64 + n * 16 + lm;
        int j = ks * 4 + lg;
        b[n] = *reinterpret_cast<const bf16x8*>(Bs + r * 64 + ((j ^ (r & 7)) << 3));
      }
#pragma unroll
      for (int m = 0; m < 4; ++m)
#pragma unroll
        for (int n = 0; n < 4; ++n)
          acc[m][n] = __builtin_amdgcn_mfma_f32_16x16x32_bf16(a[m], b[n], acc[m][n], 0, 0, 0);
    }
  }
#pragma unroll
  for (int m = 0; m < 4; ++m) {
    int row = m0 + wr * 64 + m * 16 + lg * 4;
#pragma unroll
    for (int n = 0; n < 4; ++n) {
      int col = n0 + wc * 64 + n * 16 + lm;
#pragma unroll
      for (int r = 0; r < 4; ++r) {
        float v = acc[m][n][r];
        if constexpr (sizeof(OutT) == 4) C[(long)(row + r) * N + col] = v;
        else                             C[(long)(row + r) * N + col] = (bf16)v;
      }
    }
  }
}

// ---------------- GQA causal flash attention, v4 ----------------
// One 64-row q-tile per block; 1024 blocks dispatched heaviest-first; 44.5 KB
// LDS -> 3 blocks/CU; single-buffered K/V, V regs prefetched one step ahead;
// setprio around MFMA; defer-max rescale.
__global__ __launch_bounds__(256, 3) void attn_kernel(const bf16* __restrict__ qkv,
                                                      bf16* __restrict__ out) {
  __shared__ __align__(16) bf16 Ks[64 * 128];
  __shared__ __align__(16) bf16 Vt[128 * PADV];
  __shared__ __align__(16) bf16 Pw[4 * 16 * PADP];

  const int bx = blockIdx.x;
  const int qt = 31 - (bx >> 5);        // heaviest q-tiles dispatch first
  const int h = bx & 31;                // head -> fixed XCD (h%8): KV L2 locality
  const int kvh = h >> 2;               // GROUPS = 4
  const int q0 = qt * 64;
  const int t = threadIdx.x, lane = t & 63, w = t >> 6;
  const int lg = lane >> 4, lm = lane & 15;
  bf16* pw = Pw + w * 16 * PADP;
  const int dchunk = t >> 4, kv4 = t & 15;     // V-staging assignment
  const bf16* kbase = qkv + K_COL + kvh * HD;
  const bf16* vbase = qkv + V_COL + kvh * HD;

  // Q fragments: A-frag layout Q[row=lm][k=ks*32+lg*8+j]
  const long qrow = q0 + w * 16 + lm;
  bf16x8 qf[4];
#pragma unroll
  for (int ks = 0; ks < 4; ++ks)
    qf[ks] = *reinterpret_cast<const bf16x8*>(qkv + qrow * QKV_N + h * HD + ks * 32 + lg * 8);

  f32x4 o[8];
#pragma unroll
  for (int i = 0; i < 8; ++i) o[i] = f32x4{0.f, 0.f, 0.f, 0.f};
  float mrow[4] = {-1e30f, -1e30f, -1e30f, -1e30f};
  float lrow[4] = {0.f, 0.f, 0.f, 0.f};

  // prologue: V(0) -> regs
  bf16x8 a0, a1, a2, a3;
  {
    const bf16* vs = vbase + (long)(kv4 * 4) * QKV_N + dchunk * 8;
    a0 = *reinterpret_cast<const bf16x8*>(vs);
    a1 = *reinterpret_cast<const bf16x8*>(vs + QKV_N);
    a2 = *reinterpret_cast<const bf16x8*>(vs + 2 * QKV_N);
    a3 = *reinterpret_cast<const bf16x8*>(vs + 3 * QKV_N);
  }

  for (int st = 0; st <= qt; ++st) {
    if (st) __syncthreads();            // A: all waves done reading Ks/Vt of st-1
    // V regs -> Vt (write-late)
#pragma unroll
    for (int e = 0; e < 8; ++e) {
      bf16x4 pk; pk[0] = a0[e]; pk[1] = a1[e]; pk[2] = a2[e]; pk[3] = a3[e];
      *reinterpret_cast<bf16x4*>(Vt + (dchunk * 8 + e) * PADV + kv4 * 4) = pk;
    }
    // K(st) -> Ks via global_load_lds, chunk-XOR swizzled source (rule #21)
    const long kv0 = (long)st * 64;
#pragma unroll
    for (int i = 0; i < 4; ++i) {
      int c = i * 256 + t;
      int r = c >> 4, jl = c & 15;
      int jg = jl ^ (r & 15);
      const bf16* src = kbase + (kv0 + r) * QKV_N + jg * 8;
      __builtin_amdgcn_global_load_lds((const __attribute__((address_space(1))) void*)src,
                                       (__attribute__((address_space(3))) void*)(Ks + c * 8), 16, 0, 0);
    }
    __syncthreads();                    // B: Vt written, Ks loaded

    // ---- S = Q @ K^T : 4 col-blocks of 16 ----
    f32x4 s[4];
#pragma unroll
    for (int cb = 0; cb < 4; ++cb) s[cb] = f32x4{0.f, 0.f, 0.f, 0.f};
    __builtin_amdgcn_s_setprio(1);
#pragma unroll
    for (int ks = 0; ks < 4; ++ks) {
#pragma unroll
      for (int cb = 0; cb < 4; ++cb) {
        bf16x8 kf = *reinterpret_cast<const bf16x8*>(
            Ks + (cb * 16 + lm) * 128 + (((ks * 4 + lg) ^ lm) << 3));
        s[cb] = __builtin_amdgcn_mfma_f32_16x16x32_bf16(qf[ks], kf, s[cb], 0, 0, 0);
      }
    }
    __builtin_amdgcn_s_setprio(0);

    // ---- early-issue V(st+1) -> regs (hides HBM latency under softmax+PV) ----
    if (st < qt) {
      const bf16* vs = vbase + ((long)(st + 1) * 64 + kv4 * 4) * QKV_N + dchunk * 8;
      a0 = *reinterpret_cast<const bf16x8*>(vs);
      a1 = *reinterpret_cast<const bf16x8*>(vs + QKV_N);
      a2 = *reinterpret_cast<const bf16x8*>(vs + 2 * QKV_N);
      a3 = *reinterpret_cast<const bf16x8*>(vs + 3 * QKV_N);
    }

    // ---- online softmax (log2 domain) ----
    const float SC = 0.12751742f;       // (1/sqrt(128)) * log2(e)
    float sl[4][4];
#pragma unroll
    for (int cb = 0; cb < 4; ++cb)
#pragma unroll
      for (int r = 0; r < 4; ++r) sl[cb][r] = s[cb][r] * SC;
    if (st == qt) {                     // diagonal tile: causal mask
#pragma unroll
      for (int cb = 0; cb < 4; ++cb)
#pragma unroll
        for (int r = 0; r < 4; ++r)
          if (cb * 16 + lm > w * 16 + lg * 4 + r) sl[cb][r] = -1e30f;
    }
    float tm[4];
#pragma unroll
    for (int r = 0; r < 4; ++r)
      tm[r] = fmaxf(fmaxf(sl[0][r], sl[1][r]), fmaxf(sl[2][r], sl[3][r]));
#pragma unroll
    for (int off = 1; off < 16; off <<= 1)
#pragma unroll
      for (int r = 0; r < 4; ++r) tm[r] = fmaxf(tm[r], __shfl_xor(tm[r], off));

    // defer-max (T13)
    bool grow = (tm[0] > mrow[0] + 8.f) || (tm[1] > mrow[1] + 8.f) ||
                (tm[2] > mrow[2] + 8.f) || (tm[3] > mrow[3] + 8.f);
    if (__any(grow)) {
      float alpha[4];
#pragma unroll
      for (int r = 0; r < 4; ++r) {
        float mnew = fmaxf(mrow[r], tm[r]);
        alpha[r] = exp2f(mrow[r] - mnew);
        mrow[r] = mnew;
        lrow[r] *= alpha[r];
      }
#pragma unroll
      for (int i = 0; i < 8; ++i)
#pragma unroll
        for (int r = 0; r < 4; ++r) o[i][r] *= alpha[r];
    }
    float p[4][4], psum[4];
#pragma unroll
    for (int r = 0; r < 4; ++r) {
#pragma unroll
      for (int cb = 0; cb < 4; ++cb) p[cb][r] = exp2f(sl[cb][r] - mrow[r]);
      psum[r] = (p[0][r] + p[1][r]) + (p[2][r] + p[3][r]);
    }
#pragma unroll
    for (int off = 1; off < 16; off <<= 1)
#pragma unroll
      for (int r = 0; r < 4; ++r) psum[r] += __shfl_xor(psum[r], off);
#pragma unroll
    for (int r = 0; r < 4; ++r) lrow[r] += psum[r];

    // ---- P -> LDS (bf16), per-wave region ----
#pragma unroll
    for (int cb = 0; cb < 4; ++cb)
#pragma unroll
      for (int r = 0; r < 4; ++r)
        pw[(lg * 4 + r) * PADP + cb * 16 + lm] = (bf16)p[cb][r];

    // ---- PV: o[db] += P[16x64] @ V[64x(db block)] ----
    bf16x8 pa0 = *reinterpret_cast<const bf16x8*>(pw + lm * PADP + lg * 8);
    bf16x8 pa1 = *reinterpret_cast<const bf16x8*>(pw + lm * PADP + 32 + lg * 8);
    __builtin_amdgcn_s_setprio(1);
#pragma unroll
    for (int db = 0; db < 8; ++db) {
      bf16x8 vf0 = *reinterpret_cast<const bf16x8*>(Vt + (db * 16 + lm) * PADV + lg * 8);
      bf16x8 vf1 = *reinterpret_cast<const bf16x8*>(Vt + (db * 16 + lm) * PADV + 32 + lg * 8);
      o[db] = __builtin_amdgcn_mfma_f32_16x16x32_bf16(pa0, vf0, o[db], 0, 0, 0);
      o[db] = __builtin_amdgcn_mfma_f32_16x16x32_bf16(pa1, vf1, o[db], 0, 0, 0);
    }
    __builtin_amdgcn_s_setprio(0);
  }

  // ---- epilogue: normalize + store bf16 [S][4096] ----
#pragma unroll
  for (int r = 0; r < 4; ++r) {
    float inv = 1.0f / lrow[r];
    long row = q0 + w * 16 + lg * 4 + r;
#pragma unroll
    for (int db = 0; db < 8; ++db)
      out[row * HID_DIM + h * HD + db * 16 + lm] = (bf16)(o[db][r] * inv);
  }
}

extern "C" void kernel_launch(void* const* d_in, const int* in_sizes, int n_in,
                              void* d_out, int out_size, void* d_ws, size_t ws_size,
                              hipStream_t stream) {
  const float* hs = (const float*)d_in[0];
  const float* Wq = (const float*)d_in[1];
  const float* Wk = (const float*)d_in[2];
  const float* Wv = (const float*)d_in[3];
  const float* Wo = (const float*)d_in[4];
  float* out = (float*)d_out;
  char* ws = (char*)d_ws;

  bf16*  hsb   = (bf16*)(ws);                    // 2048x4096 bf16
  bf16*  wqkvb = (bf16*)(ws + 16777216);         // 6144x4096 bf16
  bf16*  wob   = (bf16*)(ws + 67108864);         // 4096x4096 bf16
  bf16*  qkv   = (bf16*)(ws + 100663296);        // 2048x6144 bf16
  bf16*  attn  = (bf16*)(ws + 125829120);        // 2048x4096 bf16
  float* cost  = (float*)(ws + 142606336);       // 2048x64 f32
  float* sint  = (float*)(ws + 143130624);       // 2048x64 f32

  cvt_f32_bf16_kernel<<<8192,  256, 0, stream>>>(hs, hsb, 2097152);
  cvt_f32_bf16_kernel<<<16384, 256, 0, stream>>>(Wq, wqkvb, 4194304);
  cvt_f32_bf16_kernel<<<4096,  256, 0, stream>>>(Wk, wqkvb + (long)4096 * 4096, 1048576);
  cvt_f32_bf16_kernel<<<4096,  256, 0, stream>>>(Wv, wqkvb + (long)5120 * 4096, 1048576);
  cvt_f32_bf16_kernel<<<16384, 256, 0, stream>>>(Wo, wob, 4194304);
  rope_table_kernel<<<512, 256, 0, stream>>>(cost, sint);
  gemm_bt_kernel<bf16><<<dim3(48, 16), 256, 0, stream>>>(hsb, wqkvb, qkv, 2048, 6144, 4096);
  rope_apply_kernel<<<2560, 256, 0, stream>>>(qkv, cost, sint);
  attn_kernel<<<1024, 256, 0, stream>>>(qkv, attn);
  gemm_bt_kernel<float><<<dim3(32, 16), 256, 0, stream>>>(attn, wob, out, 2048, 4096, 4096);
}

// Round 5
// 328.755 us; speedup vs baseline: 2.0600x; 1.1245x over previous
//
#include <hip/hip_runtime.h>

typedef __bf16 bf16;
typedef __bf16 bf16x4 __attribute__((ext_vector_type(4)));
typedef __bf16 bf16x8 __attribute__((ext_vector_type(8)));
typedef float f32x4 __attribute__((ext_vector_type(4)));

#define S_LEN 2048
#define HID_DIM 4096
#define NH 32
#define NKV 8
#define HD 128
#define QKV_N 6144   // 4096 Q + 1024 K + 1024 V
#define K_COL 4096
#define V_COL 5120
#define PADV 76

// ---------------- fused fp32 -> bf16 conversion for all 5 inputs ----------------
// segments (float4 units): hs 2097152 | Wq 4194304 | Wk 1048576 | Wv 1048576 | Wo 4194304
__global__ void cvt_all_kernel(const float* __restrict__ hs, const float* __restrict__ wq,
                               const float* __restrict__ wk, const float* __restrict__ wv,
                               const float* __restrict__ wo, bf16* __restrict__ hsb,
                               bf16* __restrict__ wqkvb, bf16* __restrict__ wob) {
  long i = (long)blockIdx.x * blockDim.x + threadIdx.x;   // < 12582912
  const float* src; bf16* dst; long off;
  if (i < 2097152)      { src = hs; dst = hsb;   off = i; }
  else if (i < 6291456) { src = wq; dst = wqkvb; off = i - 2097152; }
  else if (i < 7340032) { src = wk; dst = wqkvb + (long)4096 * 4096 / 4 * 4; off = i - 6291456; dst = wqkvb + (long)4096 * 4096; }
  else if (i < 8388608) { src = wv; dst = wqkvb + (long)5120 * 4096; off = i - 7340032; }
  else                  { src = wo; dst = wob;   off = i - 8388608; }
  float4 v = reinterpret_cast<const float4*>(src)[off];
  bf16x4 o;
  o[0] = (bf16)v.x; o[1] = (bf16)v.y; o[2] = (bf16)v.z; o[3] = (bf16)v.w;
  reinterpret_cast<bf16x4*>(dst)[off] = o;
}

// ---------------- RoPE tables: cos/sin [S][64] fp32 ----------------
__global__ void rope_table_kernel(float* __restrict__ cost, float* __restrict__ sint) {
  int i = blockIdx.x * blockDim.x + threadIdx.x;   // 2048*64
  int s = i >> 6, d = i & 63;
  float inv = expf(-0.14391156831212787f * (float)d);   // 10000^(-d/64)
  float ang = (float)s * inv;
  cost[i] = cosf(ang);
  sint[i] = sinf(ang);
}

// ---------------- RoPE apply in-place, vectorized bf16x8 ----------------
__global__ void rope_apply_kernel(bf16* __restrict__ qkv, const float* __restrict__ cost,
                                  const float* __restrict__ sint) {
  int idx = blockIdx.x * blockDim.x + threadIdx.x;  // 2048 rows * 320 chunks
  int s = idx / 320;
  int c = idx - s * 320;
  int g = c >> 3, dc = (c & 7) * 8;      // head-slot 0..39, d-chunk of 8 within 0..63
  long base = (long)s * QKV_N + g * 128 + dc;
  bf16x8 x1 = *reinterpret_cast<const bf16x8*>(qkv + base);
  bf16x8 x2 = *reinterpret_cast<const bf16x8*>(qkv + base + 64);
  const float* cp = cost + (s << 6) + dc;
  const float* sp = sint + (s << 6) + dc;
  float4 ca = *reinterpret_cast<const float4*>(cp);
  float4 cb = *reinterpret_cast<const float4*>(cp + 4);
  float4 sa = *reinterpret_cast<const float4*>(sp);
  float4 sb = *reinterpret_cast<const float4*>(sp + 4);
  float co[8] = {ca.x, ca.y, ca.z, ca.w, cb.x, cb.y, cb.z, cb.w};
  float sn[8] = {sa.x, sa.y, sa.z, sa.w, sb.x, sb.y, sb.z, sb.w};
  bf16x8 y1, y2;
#pragma unroll
  for (int e = 0; e < 8; ++e) {
    float a = (float)x1[e], b = (float)x2[e];
    y1[e] = (bf16)(a * co[e] - b * sn[e]);
    y2[e] = (bf16)(b * co[e] + a * sn[e]);
  }
  *reinterpret_cast<bf16x8*>(qkv + base)      = y1;
  *reinterpret_cast<bf16x8*>(qkv + base + 64) = y2;
}

// ---------------- bf16 GEMM, C[M,N] = A[M,K] @ B[N,K]^T (m97 structure) ----------------
template<typename OutT>
__global__ __launch_bounds__(256, 2) void gemm_bt_kernel(
    const bf16* __restrict__ A, const bf16* __restrict__ B, OutT* __restrict__ C,
    int M, int N, int K) {
  __shared__ __align__(16) bf16 As[128 * 64];
  __shared__ __align__(16) bf16 Bs[128 * 64];

  int nwg = gridDim.x * gridDim.y;
  int bid = blockIdx.y * gridDim.x + blockIdx.x;
  int cpx = nwg >> 3;
  int swz = (bid & 7) * cpx + (bid >> 3);
  int bx = swz % gridDim.x, by = swz / gridDim.x;
  const int n0 = bx * 128, m0 = by * 128;

  const int t = threadIdx.x;
  const int lane = t & 63, w = t >> 6;
  const int wr = w >> 1, wc = w & 1;
  const int lg = lane >> 4, lm = lane & 15;
  f32x4 acc[4][4] = {};

  for (int k0 = 0; k0 < K; k0 += 64) {
    __syncthreads();
#pragma unroll
    for (int i = 0; i < 4; ++i) {
      int c = i * 256 + t;
      int r = c >> 3, jl = c & 7;
      int jg = jl ^ (r & 7);
      const bf16* srcA = A + (long)(m0 + r) * K + k0 + jg * 8;
      __builtin_amdgcn_global_load_lds((const __attribute__((address_space(1))) void*)srcA,
                                       (__attribute__((address_space(3))) void*)(As + c * 8), 16, 0, 0);
      const bf16* srcB = B + (long)(n0 + r) * K + k0 + jg * 8;
      __builtin_amdgcn_global_load_lds((const __attribute__((address_space(1))) void*)srcB,
                                       (__attribute__((address_space(3))) void*)(Bs + c * 8), 16, 0, 0);
    }
    __syncthreads();
#pragma unroll
    for (int ks = 0; ks < 2; ++ks) {
      bf16x8 a[4], b[4];
#pragma unroll
      for (int m = 0; m < 4; ++m) {
        int r = wr * 64 + m * 16 + lm;
        int j = ks * 4 + lg;
        a[m] = *reinterpret_cast<const bf16x8*>(As + r * 64 + ((j ^ (r & 7)) << 3));
      }
#pragma unroll
      for (int n = 0; n < 4; ++n) {
        int r = wc * 64 + n * 16 + lm;
        int j = ks * 4 + lg;
        b[n] = *reinterpret_cast<const bf16x8*>(Bs + r * 64 + ((j ^ (r & 7)) << 3));
      }
#pragma unroll
      for (int m = 0; m < 4; ++m)
#pragma unroll
        for (int n = 0; n < 4; ++n)
          acc[m][n] = __builtin_amdgcn_mfma_f32_16x16x32_bf16(a[m], b[n], acc[m][n], 0, 0, 0);
    }
  }
#pragma unroll
  for (int m = 0; m < 4; ++m) {
    int row = m0 + wr * 64 + m * 16 + lg * 4;
#pragma unroll
    for (int n = 0; n < 4; ++n) {
      int col = n0 + wc * 64 + n * 16 + lm;
#pragma unroll
      for (int r = 0; r < 4; ++r) {
        float v = acc[m][n][r];
        if constexpr (sizeof(OutT) == 4) C[(long)(row + r) * N + col] = v;
        else                             C[(long)(row + r) * N + col] = (bf16)v;
      }
    }
  }
}

// ---------------- GQA causal flash attention, v5 ----------------
// Swapped QK^T (S^T via mfma(K,Q)): each lane owns one q-row -> in-register
// softmax (2 shfl per reduction). Zero-shuffle P->PV via K-window permutation
// applied to BOTH P (trivially, own regs) and Vt (at staging). Ks double-buffer
// with post-barrier prefetch. One q-tile/block, heaviest-first, h->XCD pinned.
__global__ __launch_bounds__(256, 3) void attn_kernel(const bf16* __restrict__ qkv,
                                                      bf16* __restrict__ out) {
  __shared__ __align__(16) bf16 Ks[2][64 * 128];
  __shared__ __align__(16) bf16 Vt[128 * PADV];

  const int bx = blockIdx.x;
  const int qt = 31 - (bx >> 5);        // heaviest q-tiles dispatch first
  const int h = bx & 31;                // head -> fixed XCD (h%8): KV L2 locality
  const int kvh = h >> 2;               // GROUPS = 4
  const int q0 = qt * 64;
  const int t = threadIdx.x, lane = t & 63, w = t >> 6;
  const int lg = lane >> 4, lm = lane & 15;
  const int dchunk = t >> 4, kv4 = t & 15;     // V-staging assignment
  // permuted column base: value V[4*kv4 + r] -> Vt column pcol+r
  const int pcol = ((kv4 >> 3) << 5) | ((kv4 & 3) << 3) | (((kv4 >> 2) & 1) << 2);
  const bf16* kbase = qkv + K_COL + kvh * HD;
  const bf16* vbase = qkv + V_COL + kvh * HD;

  // Q fragments (B-frag): lane lm holds Q[q=q0+w*16+lm][k=ks*32+lg*8+j]
  const long qrow = q0 + w * 16 + lm;
  bf16x8 qf[4];
#pragma unroll
  for (int ks = 0; ks < 4; ++ks)
    qf[ks] = *reinterpret_cast<const bf16x8*>(qkv + qrow * QKV_N + h * HD + ks * 32 + lg * 8);

  f32x4 o[8];
#pragma unroll
  for (int i = 0; i < 8; ++i) o[i] = f32x4{0.f, 0.f, 0.f, 0.f};
  float mrow = -1e30f, lrow = 0.f;      // per-lane: q-row = q0 + w*16 + lm

  // ---- prologue: issue K(0) -> Ks[0]; load V(0) -> regs ----
  bf16x8 a0, a1, a2, a3;
  {
#pragma unroll
    for (int i = 0; i < 4; ++i) {
      int c = i * 256 + t;
      int r = c >> 4, jl = c & 15;
      int jg = jl ^ (r & 15);
      const bf16* src = kbase + (long)r * QKV_N + jg * 8;
      __builtin_amdgcn_global_load_lds((const __attribute__((address_space(1))) void*)src,
                                       (__attribute__((address_space(3))) void*)(Ks[0] + c * 8), 16, 0, 0);
    }
    const bf16* vs = vbase + (long)(kv4 * 4) * QKV_N + dchunk * 8;
    a0 = *reinterpret_cast<const bf16x8*>(vs);
    a1 = *reinterpret_cast<const bf16x8*>(vs + QKV_N);
    a2 = *reinterpret_cast<const bf16x8*>(vs + 2 * QKV_N);
    a3 = *reinterpret_cast<const bf16x8*>(vs + 3 * QKV_N);
  }

  for (int st = 0; st <= qt; ++st) {
    const int cur = st & 1;
    // ---- write V(st) regs -> Vt at permuted columns (compiler waits V vmcnt) ----
#pragma unroll
    for (int e = 0; e < 8; ++e) {
      bf16x4 pk; pk[0] = a0[e]; pk[1] = a1[e]; pk[2] = a2[e]; pk[3] = a3[e];
      *reinterpret_cast<bf16x4*>(Vt + (dchunk * 8 + e) * PADV + pcol) = pk;
    }
    __syncthreads();      // drains K(st) gload_lds; publishes Vt(st)

    // ---- issue K(st+1) -> Ks[cur^1] and V(st+1) -> regs (hidden under compute) ----
    if (st < qt) {
      const long kv0n = (long)(st + 1) * 64;
#pragma unroll
      for (int i = 0; i < 4; ++i) {
        int c = i * 256 + t;
        int r = c >> 4, jl = c & 15;
        int jg = jl ^ (r & 15);
        const bf16* src = kbase + (kv0n + r) * QKV_N + jg * 8;
        __builtin_amdgcn_global_load_lds((const __attribute__((address_space(1))) void*)src,
                                         (__attribute__((address_space(3))) void*)(Ks[cur ^ 1] + c * 8), 16, 0, 0);
      }
      const bf16* vs = vbase + (kv0n + kv4 * 4) * QKV_N + dchunk * 8;
      a0 = *reinterpret_cast<const bf16x8*>(vs);
      a1 = *reinterpret_cast<const bf16x8*>(vs + QKV_N);
      a2 = *reinterpret_cast<const bf16x8*>(vs + 2 * QKV_N);
      a3 = *reinterpret_cast<const bf16x8*>(vs + 3 * QKV_N);
    }

    // ---- S^T = K @ Q^T : lane lm owns q-row, kv = cb*16 + lg*4 + r ----
    f32x4 s[4];
#pragma unroll
    for (int cb = 0; cb < 4; ++cb) s[cb] = f32x4{0.f, 0.f, 0.f, 0.f};
    __builtin_amdgcn_s_setprio(1);
#pragma unroll
    for (int ks = 0; ks < 4; ++ks) {
#pragma unroll
      for (int cb = 0; cb < 4; ++cb) {
        bf16x8 kf = *reinterpret_cast<const bf16x8*>(
            Ks[cur] + (cb * 16 + lm) * 128 + (((ks * 4 + lg) ^ lm) << 3));
        s[cb] = __builtin_amdgcn_mfma_f32_16x16x32_bf16(kf, qf[ks], s[cb], 0, 0, 0);
      }
    }
    __builtin_amdgcn_s_setprio(0);

    // ---- in-register online softmax (log2 domain) ----
    const float SC = 0.12751742f;       // (1/sqrt(128)) * log2(e)
    const int kv0 = st * 64;
    const int qg = q0 + w * 16 + lm;    // my q-row (global)
    float sl[4][4];
#pragma unroll
    for (int cb = 0; cb < 4; ++cb)
#pragma unroll
      for (int r = 0; r < 4; ++r) {
        float v = s[cb][r] * SC;
        if (st == qt && (kv0 + cb * 16 + lg * 4 + r) > qg) v = -1e30f;
        sl[cb][r] = v;
      }
    float tm = sl[0][0];
#pragma unroll
    for (int cb = 0; cb < 4; ++cb)
#pragma unroll
      for (int r = 0; r < 4; ++r) tm = fmaxf(tm, sl[cb][r]);
    tm = fmaxf(tm, __shfl_xor(tm, 16));
    tm = fmaxf(tm, __shfl_xor(tm, 32));

    // defer-max (T13): rescale only when the running max grew past threshold
    if (__any(tm > mrow + 8.f)) {
      float mnew = fmaxf(mrow, tm);
      float alpha = exp2f(mrow - mnew);
      mrow = mnew;
      lrow *= alpha;
      float ar[4];
#pragma unroll
      for (int r = 0; r < 4; ++r)
        ar[r] = __shfl(alpha, (lane & 48) | (lg * 4 + r));
#pragma unroll
      for (int i = 0; i < 8; ++i)
#pragma unroll
        for (int r = 0; r < 4; ++r) o[i][r] *= ar[r];
    }
    float p[4][4];
    float psum = 0.f;
#pragma unroll
    for (int cb = 0; cb < 4; ++cb)
#pragma unroll
      for (int r = 0; r < 4; ++r) {
        p[cb][r] = exp2f(sl[cb][r] - mrow);
        psum += p[cb][r];
      }
    psum += __shfl_xor(psum, 16);
    psum += __shfl_xor(psum, 32);
    lrow += psum;

    // ---- P A-frags directly from registers (K-window permutation matches Vt) ----
    bf16x8 pa0, pa1;
#pragma unroll
    for (int r = 0; r < 4; ++r) {
      pa0[r]     = (bf16)p[0][r];
      pa0[4 + r] = (bf16)p[1][r];
      pa1[r]     = (bf16)p[2][r];
      pa1[4 + r] = (bf16)p[3][r];
    }

    // ---- PV: o[db] += P[16x64] @ V[64 x 16d] ----
    __builtin_amdgcn_s_setprio(1);
#pragma unroll
    for (int db = 0; db < 8; ++db) {
      bf16x8 vf0 = *reinterpret_cast<const bf16x8*>(Vt + (db * 16 + lm) * PADV + lg * 8);
      bf16x8 vf1 = *reinterpret_cast<const bf16x8*>(Vt + (db * 16 + lm) * PADV + 32 + lg * 8);
      o[db] = __builtin_amdgcn_mfma_f32_16x16x32_bf16(pa0, vf0, o[db], 0, 0, 0);
      o[db] = __builtin_amdgcn_mfma_f32_16x16x32_bf16(pa1, vf1, o[db], 0, 0, 0);
    }
    __builtin_amdgcn_s_setprio(0);

    if (st < qt) __syncthreads();       // Vt reads done before next write
  }

  // ---- epilogue: normalize + store bf16 [S][4096] ----
  float invr[4];
#pragma unroll
  for (int r = 0; r < 4; ++r)
    invr[r] = 1.0f / __shfl(lrow, (lane & 48) | (lg * 4 + r));
#pragma unroll
  for (int r = 0; r < 4; ++r) {
    long row = q0 + w * 16 + lg * 4 + r;
#pragma unroll
    for (int db = 0; db < 8; ++db)
      out[row * HID_DIM + h * HD + db * 16 + lm] = (bf16)(o[db][r] * invr[r]);
  }
}

extern "C" void kernel_launch(void* const* d_in, const int* in_sizes, int n_in,
                              void* d_out, int out_size, void* d_ws, size_t ws_size,
                              hipStream_t stream) {
  const float* hs = (const float*)d_in[0];
  const float* Wq = (const float*)d_in[1];
  const float* Wk = (const float*)d_in[2];
  const float* Wv = (const float*)d_in[3];
  const float* Wo = (const float*)d_in[4];
  float* out = (float*)d_out;
  char* ws = (char*)d_ws;

  bf16*  hsb   = (bf16*)(ws);                    // 2048x4096 bf16
  bf16*  wqkvb = (bf16*)(ws + 16777216);         // 6144x4096 bf16
  bf16*  wob   = (bf16*)(ws + 67108864);         // 4096x4096 bf16
  bf16*  qkv   = (bf16*)(ws + 100663296);        // 2048x6144 bf16
  bf16*  attn  = (bf16*)(ws + 125829120);        // 2048x4096 bf16
  float* cost  = (float*)(ws + 142606336);       // 2048x64 f32
  float* sint  = (float*)(ws + 143130624);       // 2048x64 f32

  cvt_all_kernel<<<49152, 256, 0, stream>>>(hs, Wq, Wk, Wv, Wo, hsb, wqkvb, wob);
  rope_table_kernel<<<512, 256, 0, stream>>>(cost, sint);
  gemm_bt_kernel<bf16><<<dim3(48, 16), 256, 0, stream>>>(hsb, wqkvb, qkv, 2048, 6144, 4096);
  rope_apply_kernel<<<2560, 256, 0, stream>>>(qkv, cost, sint);
  attn_kernel<<<1024, 256, 0, stream>>>(qkv, attn);
  gemm_bt_kernel<float><<<dim3(32, 16), 256, 0, stream>>>(attn, wob, out, 2048, 4096, 4096);
}

// Round 6
// 321.123 us; speedup vs baseline: 2.1089x; 1.0238x over previous
//
#include <hip/hip_runtime.h>

typedef __bf16 bf16;
typedef __bf16 bf16x2 __attribute__((ext_vector_type(2)));
typedef __bf16 bf16x4 __attribute__((ext_vector_type(4)));
typedef __bf16 bf16x8 __attribute__((ext_vector_type(8)));
typedef float f32x4 __attribute__((ext_vector_type(4)));

#define S_LEN 2048
#define HID_DIM 4096
#define NH 32
#define NKV 8
#define HD 128
#define QKV_N 6144   // 4096 Q + 1024 K + 1024 V
#define K_COL 4096
#define V_COL 5120
#define PADV 76

// ---------------- fused fp32 -> bf16 conversion for all 5 inputs ----------------
__global__ void cvt_all_kernel(const float* __restrict__ hs, const float* __restrict__ wq,
                               const float* __restrict__ wk, const float* __restrict__ wv,
                               const float* __restrict__ wo, bf16* __restrict__ hsb,
                               bf16* __restrict__ wqkvb, bf16* __restrict__ wob) {
  long i = (long)blockIdx.x * blockDim.x + threadIdx.x;   // < 12582912
  const float* src; bf16* dst; long off;
  if (i < 2097152)      { src = hs; dst = hsb;                          off = i; }
  else if (i < 6291456) { src = wq; dst = wqkvb;                        off = i - 2097152; }
  else if (i < 7340032) { src = wk; dst = wqkvb + (long)4096 * 4096;    off = i - 6291456; }
  else if (i < 8388608) { src = wv; dst = wqkvb + (long)5120 * 4096;    off = i - 7340032; }
  else                  { src = wo; dst = wob;                          off = i - 8388608; }
  float4 v = reinterpret_cast<const float4*>(src)[off];
  bf16x4 o;
  o[0] = (bf16)v.x; o[1] = (bf16)v.y; o[2] = (bf16)v.z; o[3] = (bf16)v.w;
  reinterpret_cast<bf16x4*>(dst)[off] = o;
}

// ---------------- RoPE tables: cos/sin [S][64] fp32 ----------------
__global__ void rope_table_kernel(float* __restrict__ cost, float* __restrict__ sint) {
  int i = blockIdx.x * blockDim.x + threadIdx.x;   // 2048*64
  int s = i >> 6, d = i & 63;
  float inv = expf(-0.14391156831212787f * (float)d);   // 10000^(-d/64)
  float ang = (float)s * inv;
  cost[i] = cosf(ang);
  sint[i] = sinf(ang);
}

// ---------------- RoPE apply in-place, vectorized bf16x8 ----------------
__global__ void rope_apply_kernel(bf16* __restrict__ qkv, const float* __restrict__ cost,
                                  const float* __restrict__ sint) {
  int idx = blockIdx.x * blockDim.x + threadIdx.x;  // 2048 rows * 320 chunks
  int s = idx / 320;
  int c = idx - s * 320;
  int g = c >> 3, dc = (c & 7) * 8;
  long base = (long)s * QKV_N + g * 128 + dc;
  bf16x8 x1 = *reinterpret_cast<const bf16x8*>(qkv + base);
  bf16x8 x2 = *reinterpret_cast<const bf16x8*>(qkv + base + 64);
  const float* cp = cost + (s << 6) + dc;
  const float* sp = sint + (s << 6) + dc;
  float4 ca = *reinterpret_cast<const float4*>(cp);
  float4 cb = *reinterpret_cast<const float4*>(cp + 4);
  float4 sa = *reinterpret_cast<const float4*>(sp);
  float4 sb = *reinterpret_cast<const float4*>(sp + 4);
  float co[8] = {ca.x, ca.y, ca.z, ca.w, cb.x, cb.y, cb.z, cb.w};
  float sn[8] = {sa.x, sa.y, sa.z, sa.w, sb.x, sb.y, sb.z, sb.w};
  bf16x8 y1, y2;
#pragma unroll
  for (int e = 0; e < 8; ++e) {
    float a = (float)x1[e], b = (float)x2[e];
    y1[e] = (bf16)(a * co[e] - b * sn[e]);
    y2[e] = (bf16)(b * co[e] + a * sn[e]);
  }
  *reinterpret_cast<bf16x8*>(qkv + base)      = y1;
  *reinterpret_cast<bf16x8*>(qkv + base + 64) = y2;
}

// ---------------- bf16 GEMM, 128^2 m97 structure (out-proj) ----------------
template<typename OutT>
__global__ __launch_bounds__(256, 2) void gemm_bt_kernel(
    const bf16* __restrict__ A, const bf16* __restrict__ B, OutT* __restrict__ C,
    int M, int N, int K) {
  __shared__ __align__(16) bf16 As[128 * 64];
  __shared__ __align__(16) bf16 Bs[128 * 64];

  int nwg = gridDim.x * gridDim.y;
  int bid = blockIdx.y * gridDim.x + blockIdx.x;
  int cpx = nwg >> 3;
  int swz = (bid & 7) * cpx + (bid >> 3);
  int bx = swz % gridDim.x, by = swz / gridDim.x;
  const int n0 = bx * 128, m0 = by * 128;

  const int t = threadIdx.x;
  const int lane = t & 63, w = t >> 6;
  const int wr = w >> 1, wc = w & 1;
  const int lg = lane >> 4, lm = lane & 15;
  f32x4 acc[4][4] = {};

  for (int k0 = 0; k0 < K; k0 += 64) {
    __syncthreads();
#pragma unroll
    for (int i = 0; i < 4; ++i) {
      int c = i * 256 + t;
      int r = c >> 3, jl = c & 7;
      int jg = jl ^ (r & 7);
      const bf16* srcA = A + (long)(m0 + r) * K + k0 + jg * 8;
      __builtin_amdgcn_global_load_lds((const __attribute__((address_space(1))) void*)srcA,
                                       (__attribute__((address_space(3))) void*)(As + c * 8), 16, 0, 0);
      const bf16* srcB = B + (long)(n0 + r) * K + k0 + jg * 8;
      __builtin_amdgcn_global_load_lds((const __attribute__((address_space(1))) void*)srcB,
                                       (__attribute__((address_space(3))) void*)(Bs + c * 8), 16, 0, 0);
    }
    __syncthreads();
#pragma unroll
    for (int ks = 0; ks < 2; ++ks) {
      bf16x8 a[4], b[4];
#pragma unroll
      for (int m = 0; m < 4; ++m) {
        int r = wr * 64 + m * 16 + lm;
        int j = ks * 4 + lg;
        a[m] = *reinterpret_cast<const bf16x8*>(As + r * 64 + ((j ^ (r & 7)) << 3));
      }
#pragma unroll
      for (int n = 0; n < 4; ++n) {
        int r = wc * 64 + n * 16 + lm;
        int j = ks * 4 + lg;
        b[n] = *reinterpret_cast<const bf16x8*>(Bs + r * 64 + ((j ^ (r & 7)) << 3));
      }
#pragma unroll
      for (int m = 0; m < 4; ++m)
#pragma unroll
        for (int n = 0; n < 4; ++n)
          acc[m][n] = __builtin_amdgcn_mfma_f32_16x16x32_bf16(a[m], b[n], acc[m][n], 0, 0, 0);
    }
  }
#pragma unroll
  for (int m = 0; m < 4; ++m) {
    int row = m0 + wr * 64 + m * 16 + lg * 4;
#pragma unroll
    for (int n = 0; n < 4; ++n) {
      int col = n0 + wc * 64 + n * 16 + lm;
#pragma unroll
      for (int r = 0; r < 4; ++r) {
        float v = acc[m][n][r];
        if constexpr (sizeof(OutT) == 4) C[(long)(row + r) * N + col] = v;
        else                             C[(long)(row + r) * N + col] = (bf16)v;
      }
    }
  }
}

// ---------------- 256^2 8-phase GEMM (QKV projection), T2+T3+T4+T5 ----------------
// 512 thr / 8 waves (2M x 4N), BK=64, LDS 128 KiB (2 K-tile bufs), raw s_barrier,
// counted vmcnt(4) at phases 4/8 only. C[M,N] = A[M,K] @ B[N,K]^T, bf16 out.
#define STG(buf, mat, kt, half) {                                                        \
  const bf16* sp_ = (mat) ? Bp : Ap;                                                     \
  int row0_ = ((mat) ? n0 : m0) + (half) * 128;                                          \
  int lb_ = (buf) * 32768 + (mat) * 16384 + (half) * 8192;                               \
  _Pragma("unroll") for (int ii_ = 0; ii_ < 2; ++ii_) {                                  \
    int c_ = ii_ * 512 + t;                                                              \
    int r_ = c_ >> 3, jl_ = c_ & 7, jg_ = jl_ ^ (r_ & 7);                                \
    const bf16* src_ = sp_ + (long)(row0_ + r_) * K + (kt) * 64 + jg_ * 8;               \
    __builtin_amdgcn_global_load_lds((const __attribute__((address_space(1))) void*)src_,\
        (__attribute__((address_space(3))) void*)(L + lb_ + c_ * 8), 16, 0, 0);          \
  } }

#define DSA(ab_, mh) {                                                                   \
  _Pragma("unroll") for (int mf_ = 0; mf_ < 4; ++mf_)                                    \
    _Pragma("unroll") for (int ks_ = 0; ks_ < 2; ++ks_) {                                \
      int R_ = wr * 128 + (mh) * 64 + mf_ * 16 + lm;                                     \
      aF[mf_][ks_] = *reinterpret_cast<const bf16x8*>(                                   \
          L + (ab_) + R_ * 64 + (((ks_ * 4 + lg) ^ (R_ & 7)) << 3));                     \
    } }

#define DSB(bb_, nh, bfr) {                                                              \
  _Pragma("unroll") for (int nf_ = 0; nf_ < 2; ++nf_)                                    \
    _Pragma("unroll") for (int ks_ = 0; ks_ < 2; ++ks_) {                                \
      int R_ = wc * 64 + (nh) * 32 + nf_ * 16 + lm;                                      \
      bfr[nf_][ks_] = *reinterpret_cast<const bf16x8*>(                                  \
          L + (bb_) + R_ * 64 + (((ks_ * 4 + lg) ^ (R_ & 7)) << 3));                     \
    } }

#define MM(mh, nh, bfr) {                                                                \
  __builtin_amdgcn_s_setprio(1);                                                         \
  _Pragma("unroll") for (int mf_ = 0; mf_ < 4; ++mf_)                                    \
    _Pragma("unroll") for (int nf_ = 0; nf_ < 2; ++nf_)                                  \
      _Pragma("unroll") for (int ks_ = 0; ks_ < 2; ++ks_)                                \
        acc[(mh) * 4 + mf_][(nh) * 2 + nf_] = __builtin_amdgcn_mfma_f32_16x16x32_bf16(   \
            aF[mf_][ks_], bfr[nf_][ks_], acc[(mh) * 4 + mf_][(nh) * 2 + nf_], 0, 0, 0);  \
  __builtin_amdgcn_s_setprio(0); }

#define BAR() __builtin_amdgcn_s_barrier()

__global__ __launch_bounds__(512, 1) void gemm256_kernel(
    const bf16* __restrict__ Ap, const bf16* __restrict__ Bp, bf16* __restrict__ C,
    int M, int N, int K) {
  __shared__ __align__(16) bf16 L[65536];   // 128 KB

  int nwg = gridDim.x * gridDim.y;
  int bid = blockIdx.y * gridDim.x + blockIdx.x;
  int cpx = nwg >> 3;
  int swz = (bid & 7) * cpx + (bid >> 3);
  int bxs = swz % gridDim.x, bys = swz / gridDim.x;
  const int n0 = bxs * 256, m0 = bys * 256;

  const int t = threadIdx.x;
  const int lane = t & 63, w = t >> 6;
  const int wr = w >> 2, wc = w & 3;        // 2M x 4N waves
  const int lg = lane >> 4, lm = lane & 15;
  const int NT = K >> 6;

  f32x4 acc[8][4] = {};
  bf16x8 aF[4][2], bF0[2][2], bF1[2][2];

  // ---- prologue: K-tile 0 (A+B) -> buf0; B of K-tile 1 -> buf1 ----
  STG(0, 0, 0, 0); STG(0, 0, 0, 1); STG(0, 1, 0, 0); STG(0, 1, 0, 1);
  STG(1, 1, 1, 0); STG(1, 1, 1, 1);
  asm volatile("s_waitcnt vmcnt(4)" ::: "memory");
  BAR();

  for (int I = 0; I < (NT >> 1); ++I) {
    const int tt = 2 * I;
    const bool pf = (I < (NT >> 1) - 1);
    // ===== K-tile tt in buf0 (phases 1-4) =====
    // ph1: quad(0,0)
    DSA(0, 0); DSB(16384, 0, bF0);
    STG(1, 0, tt + 1, 0);
    BAR();
    MM(0, 0, bF0);
    BAR();
    // ph2: quad(0,1)
    DSB(16384, 1, bF1);
    STG(1, 0, tt + 1, 1);
    BAR();
    MM(0, 1, bF1);
    BAR();
    // ph3: quad(1,0)
    DSA(0, 1);
    if (pf) STG(0, 1, tt + 2, 0);
    BAR();
    MM(1, 0, bF0);
    BAR();
    // ph4: quad(1,1)
    if (pf) STG(0, 1, tt + 2, 1);
    BAR();
    MM(1, 1, bF1);
    if (pf) asm volatile("s_waitcnt vmcnt(4)" ::: "memory");
    else    asm volatile("s_waitcnt vmcnt(0)" ::: "memory");
    BAR();
    // ===== K-tile tt+1 in buf1 (phases 5-8) =====
    // ph5
    DSA(32768, 0); DSB(49152, 0, bF0);
    if (pf) STG(0, 0, tt + 2, 0);
    BAR();
    MM(0, 0, bF0);
    BAR();
    // ph6
    DSB(49152, 1, bF1);
    if (pf) STG(0, 0, tt + 2, 1);
    BAR();
    MM(0, 1, bF1);
    BAR();
    // ph7
    DSA(32768, 1);
    if (pf) STG(1, 1, tt + 3, 0);
    BAR();
    MM(1, 0, bF0);
    BAR();
    // ph8
    if (pf) STG(1, 1, tt + 3, 1);
    BAR();
    MM(1, 1, bF1);
    if (pf) asm volatile("s_waitcnt vmcnt(4)" ::: "memory");
    else    asm volatile("s_waitcnt vmcnt(0)" ::: "memory");
    BAR();
  }

  // ---- epilogue ----
#pragma unroll
  for (int am = 0; am < 8; ++am) {
    int row = m0 + wr * 128 + am * 16 + lg * 4;
#pragma unroll
    for (int an = 0; an < 4; ++an) {
      int col = n0 + wc * 64 + an * 16 + lm;
#pragma unroll
      for (int rr = 0; rr < 4; ++rr)
        C[(long)(row + rr) * N + col] = (bf16)acc[am][an][rr];
    }
  }
}

// ---------------- GQA causal flash attention, v6: 128-row q-tiles, 8 waves ----------------
__global__ __launch_bounds__(512, 4) void attn_kernel(const bf16* __restrict__ qkv,
                                                      bf16* __restrict__ out) {
  __shared__ __align__(16) bf16 Ks[2][64 * 128];
  __shared__ __align__(16) bf16 Vt[128 * PADV];

  const int bx = blockIdx.x;
  const int qt = 15 - (bx >> 5);        // heaviest q-tiles dispatch first
  const int h = bx & 31;                // head -> fixed XCD: KV L2 locality
  const int kvh = h >> 2;               // GROUPS = 4
  const int q0 = qt * 128;
  const int t = threadIdx.x, lane = t & 63, w = t >> 6;   // 8 waves
  const int lg = lane >> 4, lm = lane & 15;
  const int dchunk = t >> 5, kv2 = t & 31;     // V-staging: rows 2*kv2..+1, d dchunk*8..+7
  // permuted slot for kv row 2*kv2 (P/V K-window permutation, pairs stay adjacent)
  const int kva = kv2 * 2;
  const int k5 = kva & 31;
  const int slot = ((kva >> 5) << 5) | (((k5 >> 2) & 3) << 3) | ((k5 >> 4) << 2) | (k5 & 3);
  const bf16* kbase = qkv + K_COL + kvh * HD;
  const bf16* vbase = qkv + V_COL + kvh * HD;

  // Q fragments (B-operand): lane lm holds Q[q=q0+w*16+lm][k=ks*32+lg*8+j]
  const long qrow = q0 + w * 16 + lm;
  bf16x8 qf[4];
#pragma unroll
  for (int ks = 0; ks < 4; ++ks)
    qf[ks] = *reinterpret_cast<const bf16x8*>(qkv + qrow * QKV_N + h * HD + ks * 32 + lg * 8);

  f32x4 o[8];
#pragma unroll
  for (int i = 0; i < 8; ++i) o[i] = f32x4{0.f, 0.f, 0.f, 0.f};
  float mrow = -1e30f, lrow = 0.f;

  // ---- prologue: issue K(0) -> Ks[0]; load V(0) -> regs ----
  bf16x8 a0, a1;
  {
#pragma unroll
    for (int i = 0; i < 2; ++i) {
      int c = i * 512 + t;
      int r = c >> 4, jl = c & 15;
      int jg = jl ^ (r & 15);
      const bf16* src = kbase + (long)r * QKV_N + jg * 8;
      __builtin_amdgcn_global_load_lds((const __attribute__((address_space(1))) void*)src,
                                       (__attribute__((address_space(3))) void*)(Ks[0] + c * 8), 16, 0, 0);
    }
    const bf16* vs = vbase + (long)kva * QKV_N + dchunk * 8;
    a0 = *reinterpret_cast<const bf16x8*>(vs);
    a1 = *reinterpret_cast<const bf16x8*>(vs + QKV_N);
  }

  const int nst = 2 * qt + 2;
  for (int st = 0; st < nst; ++st) {
    const int cur = st & 1;
    // ---- write V(st) regs -> Vt at permuted slots ----
#pragma unroll
    for (int e = 0; e < 8; ++e) {
      bf16x2 pk; pk[0] = a0[e]; pk[1] = a1[e];
      *reinterpret_cast<bf16x2*>(Vt + (dchunk * 8 + e) * PADV + slot) = pk;
    }
    __syncthreads();      // drains K(st) gload_lds; publishes Vt(st)

    // ---- issue K(st+1) -> Ks[cur^1], V(st+1) -> regs ----
    if (st + 1 < nst) {
      const long kv0n = (long)(st + 1) * 64;
#pragma unroll
      for (int i = 0; i < 2; ++i) {
        int c = i * 512 + t;
        int r = c >> 4, jl = c & 15;
        int jg = jl ^ (r & 15);
        const bf16* src = kbase + (kv0n + r) * QKV_N + jg * 8;
        __builtin_amdgcn_global_load_lds((const __attribute__((address_space(1))) void*)src,
                                         (__attribute__((address_space(3))) void*)(Ks[cur ^ 1] + c * 8), 16, 0, 0);
      }
      const bf16* vs = vbase + (kv0n + kva) * QKV_N + dchunk * 8;
      a0 = *reinterpret_cast<const bf16x8*>(vs);
      a1 = *reinterpret_cast<const bf16x8*>(vs + QKV_N);
    }

    const int kv0 = st * 64;
    const int qg = q0 + w * 16 + lm;    // my q-row
    if (kv0 <= q0 + w * 16 + 15) {      // wave-uniform: skip fully-masked waves
      // ---- S^T = K @ Q^T ----
      f32x4 s[4];
#pragma unroll
      for (int cb = 0; cb < 4; ++cb) s[cb] = f32x4{0.f, 0.f, 0.f, 0.f};
      __builtin_amdgcn_s_setprio(1);
#pragma unroll
      for (int ks = 0; ks < 4; ++ks) {
#pragma unroll
        for (int cb = 0; cb < 4; ++cb) {
          bf16x8 kf = *reinterpret_cast<const bf16x8*>(
              Ks[cur] + (cb * 16 + lm) * 128 + (((ks * 4 + lg) ^ lm) << 3));
          s[cb] = __builtin_amdgcn_mfma_f32_16x16x32_bf16(kf, qf[ks], s[cb], 0, 0, 0);
        }
      }
      __builtin_amdgcn_s_setprio(0);

      // ---- in-register online softmax (log2 domain) ----
      const float SC = 0.12751742f;     // (1/sqrt(128)) * log2(e)
      float sl[4][4];
#pragma unroll
      for (int cb = 0; cb < 4; ++cb)
#pragma unroll
        for (int r = 0; r < 4; ++r) {
          float v = s[cb][r] * SC;
          if (st >= nst - 2 && (kv0 + cb * 16 + lg * 4 + r) > qg) v = -1e30f;
          sl[cb][r] = v;
        }
      float tm = sl[0][0];
#pragma unroll
      for (int cb = 0; cb < 4; ++cb)
#pragma unroll
        for (int r = 0; r < 4; ++r) tm = fmaxf(tm, sl[cb][r]);
      tm = fmaxf(tm, __shfl_xor(tm, 16));
      tm = fmaxf(tm, __shfl_xor(tm, 32));

      if (__any(tm > mrow + 8.f)) {     // defer-max (T13)
        float mnew = fmaxf(mrow, tm);
        float alpha = exp2f(mrow - mnew);
        mrow = mnew;
        lrow *= alpha;
        float ar[4];
#pragma unroll
        for (int r = 0; r < 4; ++r)
          ar[r] = __shfl(alpha, (lane & 48) | (lg * 4 + r));
#pragma unroll
        for (int i = 0; i < 8; ++i)
#pragma unroll
          for (int r = 0; r < 4; ++r) o[i][r] *= ar[r];
      }
      float p[4][4];
      float psum = 0.f;
#pragma unroll
      for (int cb = 0; cb < 4; ++cb)
#pragma unroll
        for (int r = 0; r < 4; ++r) {
          p[cb][r] = exp2f(sl[cb][r] - mrow);
          psum += p[cb][r];
        }
      psum += __shfl_xor(psum, 16);
      psum += __shfl_xor(psum, 32);
      lrow += psum;

      // ---- P A-frags directly from registers (permutation matches Vt) ----
      bf16x8 pa0, pa1;
#pragma unroll
      for (int r = 0; r < 4; ++r) {
        pa0[r]     = (bf16)p[0][r];
        pa0[4 + r] = (bf16)p[1][r];
        pa1[r]     = (bf16)p[2][r];
        pa1[4 + r] = (bf16)p[3][r];
      }

      // ---- PV ----
      __builtin_amdgcn_s_setprio(1);
#pragma unroll
      for (int db = 0; db < 8; ++db) {
        bf16x8 vf0 = *reinterpret_cast<const bf16x8*>(Vt + (db * 16 + lm) * PADV + lg * 8);
        bf16x8 vf1 = *reinterpret_cast<const bf16x8*>(Vt + (db * 16 + lm) * PADV + 32 + lg * 8);
        o[db] = __builtin_amdgcn_mfma_f32_16x16x32_bf16(pa0, vf0, o[db], 0, 0, 0);
        o[db] = __builtin_amdgcn_mfma_f32_16x16x32_bf16(pa1, vf1, o[db], 0, 0, 0);
      }
      __builtin_amdgcn_s_setprio(0);
    }

    if (st + 1 < nst) __syncthreads();  // Vt reads done before next V-write
  }

  // ---- epilogue: normalize + store bf16 [S][4096] ----
  float invr[4];
#pragma unroll
  for (int r = 0; r < 4; ++r)
    invr[r] = 1.0f / __shfl(lrow, (lane & 48) | (lg * 4 + r));
#pragma unroll
  for (int r = 0; r < 4; ++r) {
    long row = q0 + w * 16 + lg * 4 + r;
#pragma unroll
    for (int db = 0; db < 8; ++db)
      out[row * HID_DIM + h * HD + db * 16 + lm] = (bf16)(o[db][r] * invr[r]);
  }
}

extern "C" void kernel_launch(void* const* d_in, const int* in_sizes, int n_in,
                              void* d_out, int out_size, void* d_ws, size_t ws_size,
                              hipStream_t stream) {
  const float* hs = (const float*)d_in[0];
  const float* Wq = (const float*)d_in[1];
  const float* Wk = (const float*)d_in[2];
  const float* Wv = (const float*)d_in[3];
  const float* Wo = (const float*)d_in[4];
  float* out = (float*)d_out;
  char* ws = (char*)d_ws;

  bf16*  hsb   = (bf16*)(ws);                    // 2048x4096 bf16
  bf16*  wqkvb = (bf16*)(ws + 16777216);         // 6144x4096 bf16
  bf16*  wob   = (bf16*)(ws + 67108864);         // 4096x4096 bf16
  bf16*  qkv   = (bf16*)(ws + 100663296);        // 2048x6144 bf16
  bf16*  attn  = (bf16*)(ws + 125829120);        // 2048x4096 bf16
  float* cost  = (float*)(ws + 142606336);       // 2048x64 f32
  float* sint  = (float*)(ws + 143130624);       // 2048x64 f32

  cvt_all_kernel<<<49152, 256, 0, stream>>>(hs, Wq, Wk, Wv, Wo, hsb, wqkvb, wob);
  rope_table_kernel<<<512, 256, 0, stream>>>(cost, sint);
  gemm256_kernel<<<dim3(24, 8), 512, 0, stream>>>(hsb, wqkvb, qkv, 2048, 6144, 4096);
  rope_apply_kernel<<<2560, 256, 0, stream>>>(qkv, cost, sint);
  attn_kernel<<<512, 512, 0, stream>>>(qkv, attn);
  gemm_bt_kernel<float><<<dim3(32, 16), 256, 0, stream>>>(attn, wob, out, 2048, 4096, 4096);
}

// Round 7
// 310.665 us; speedup vs baseline: 2.1799x; 1.0337x over previous
//
#include <hip/hip_runtime.h>

typedef __bf16 bf16;
typedef __bf16 bf16x2 __attribute__((ext_vector_type(2)));
typedef __bf16 bf16x4 __attribute__((ext_vector_type(4)));
typedef __bf16 bf16x8 __attribute__((ext_vector_type(8)));
typedef float f32x4 __attribute__((ext_vector_type(4)));

#define S_LEN 2048
#define HID_DIM 4096
#define NH 32
#define NKV 8
#define HD 128
#define QKV_N 6144   // 4096 Q + 1024 K + 1024 V
#define K_COL 4096
#define V_COL 5120
#define PADV 76

// ---------------- fused fp32 -> bf16 conversion for all 5 inputs ----------------
__global__ void cvt_all_kernel(const float* __restrict__ hs, const float* __restrict__ wq,
                               const float* __restrict__ wk, const float* __restrict__ wv,
                               const float* __restrict__ wo, bf16* __restrict__ hsb,
                               bf16* __restrict__ wqkvb, bf16* __restrict__ wob) {
  long i = (long)blockIdx.x * blockDim.x + threadIdx.x;   // < 12582912
  const float* src; bf16* dst; long off;
  if (i < 2097152)      { src = hs; dst = hsb;                          off = i; }
  else if (i < 6291456) { src = wq; dst = wqkvb;                        off = i - 2097152; }
  else if (i < 7340032) { src = wk; dst = wqkvb + (long)4096 * 4096;    off = i - 6291456; }
  else if (i < 8388608) { src = wv; dst = wqkvb + (long)5120 * 4096;    off = i - 7340032; }
  else                  { src = wo; dst = wob;                          off = i - 8388608; }
  float4 v = reinterpret_cast<const float4*>(src)[off];
  bf16x4 o;
  o[0] = (bf16)v.x; o[1] = (bf16)v.y; o[2] = (bf16)v.z; o[3] = (bf16)v.w;
  reinterpret_cast<bf16x4*>(dst)[off] = o;
}

// ---------------- RoPE tables: cos/sin [S][64] fp32 ----------------
__global__ void rope_table_kernel(float* __restrict__ cost, float* __restrict__ sint) {
  int i = blockIdx.x * blockDim.x + threadIdx.x;   // 2048*64
  int s = i >> 6, d = i & 63;
  float inv = expf(-0.14391156831212787f * (float)d);   // 10000^(-d/64)
  float ang = (float)s * inv;
  cost[i] = cosf(ang);
  sint[i] = sinf(ang);
}

// ---------------- RoPE apply in-place, vectorized bf16x8 ----------------
__global__ void rope_apply_kernel(bf16* __restrict__ qkv, const float* __restrict__ cost,
                                  const float* __restrict__ sint) {
  int idx = blockIdx.x * blockDim.x + threadIdx.x;  // 2048 rows * 320 chunks
  int s = idx / 320;
  int c = idx - s * 320;
  int g = c >> 3, dc = (c & 7) * 8;
  long base = (long)s * QKV_N + g * 128 + dc;
  bf16x8 x1 = *reinterpret_cast<const bf16x8*>(qkv + base);
  bf16x8 x2 = *reinterpret_cast<const bf16x8*>(qkv + base + 64);
  const float* cp = cost + (s << 6) + dc;
  const float* sp = sint + (s << 6) + dc;
  float4 ca = *reinterpret_cast<const float4*>(cp);
  float4 cb = *reinterpret_cast<const float4*>(cp + 4);
  float4 sa = *reinterpret_cast<const float4*>(sp);
  float4 sb = *reinterpret_cast<const float4*>(sp + 4);
  float co[8] = {ca.x, ca.y, ca.z, ca.w, cb.x, cb.y, cb.z, cb.w};
  float sn[8] = {sa.x, sa.y, sa.z, sa.w, sb.x, sb.y, sb.z, sb.w};
  bf16x8 y1, y2;
#pragma unroll
  for (int e = 0; e < 8; ++e) {
    float a = (float)x1[e], b = (float)x2[e];
    y1[e] = (bf16)(a * co[e] - b * sn[e]);
    y2[e] = (bf16)(b * co[e] + a * sn[e]);
  }
  *reinterpret_cast<bf16x8*>(qkv + base)      = y1;
  *reinterpret_cast<bf16x8*>(qkv + base + 64) = y2;
}

// ---------------- 8-phase GEMM template: BM=256, BN=NB*64, BK=64 ----------------
// 512 thr / 8 waves (2M x 4N); staging in 64-row units (1 gload_lds/thread);
// counted vmcnt(NB) at phases 4/8; both-sides chunk-XOR swizzle; grid must be
// (N/(NB*64)) x (M/256) with nwg % 8 == 0. C[M,N] = A[M,K] @ B[N,K]^T.
#define STG8(buf, mat, kt, unit) {                                                       \
    const bf16* sp_ = (mat) ? Bp : Ap;                                                   \
    int row0_ = ((mat) ? n0 : m0) + (unit) * 64;                                         \
    int lb_ = (buf) * LBUF + (mat) * 16384 + (unit) * 4096;                              \
    int r_ = t >> 3, jl_ = t & 7, jg_ = jl_ ^ (r_ & 7);                                  \
    const bf16* src_ = sp_ + (long)(row0_ + r_) * K + (kt) * 64 + jg_ * 8;               \
    __builtin_amdgcn_global_load_lds((const __attribute__((address_space(1))) void*)src_,\
        (__attribute__((address_space(3))) void*)(L + lb_ + t * 8), 16, 0, 0); }

#define DSA8(buf, mh, ks) {                                                              \
    _Pragma("unroll") for (int mf_ = 0; mf_ < 4; ++mf_) {                                \
      int R_ = wr * 128 + (mh) * 64 + mf_ * 16 + lm;                                     \
      aF[mf_] = *reinterpret_cast<const bf16x8*>(                                        \
          L + (buf) * LBUF + R_ * 64 + ((((ks) * 4 + lg) ^ (R_ & 7)) << 3));             \
    } }

#define DSB8(buf) {                                                                      \
    _Pragma("unroll") for (int ks_ = 0; ks_ < 2; ++ks_)                                  \
      _Pragma("unroll") for (int nf_ = 0; nf_ < NB; ++nf_) {                             \
        int R_ = wc * (NB * 16) + nf_ * 16 + lm;                                         \
        bF[ks_][nf_] = *reinterpret_cast<const bf16x8*>(                                 \
            L + (buf) * LBUF + 16384 + R_ * 64 + (((ks_ * 4 + lg) ^ (R_ & 7)) << 3));    \
      } }

#define MM8(mh, ks) {                                                                    \
    __builtin_amdgcn_s_setprio(1);                                                       \
    _Pragma("unroll") for (int mf_ = 0; mf_ < 4; ++mf_)                                  \
      _Pragma("unroll") for (int nf_ = 0; nf_ < NB; ++nf_)                               \
        acc[(mh) * 4 + mf_][nf_] = __builtin_amdgcn_mfma_f32_16x16x32_bf16(              \
            aF[mf_], bF[ks][nf_], acc[(mh) * 4 + mf_][nf_], 0, 0, 0);                    \
    __builtin_amdgcn_s_setprio(0); }

#define BAR() __builtin_amdgcn_s_barrier()
#define WVM(n) asm volatile("s_waitcnt vmcnt(%0)" :: "i"(n) : "memory")

template<int NB, typename OutT>
__global__ __launch_bounds__(512, 1) void gemm8p_kernel(
    const bf16* __restrict__ Ap, const bf16* __restrict__ Bp, OutT* __restrict__ C,
    int M, int N, int K) {
  constexpr int LBUF = 16384 + NB * 4096;     // bf16 elems per K-tile buffer
  __shared__ __align__(16) bf16 L[2 * LBUF];

  int nwg = gridDim.x * gridDim.y;
  int bid = blockIdx.y * gridDim.x + blockIdx.x;
  int cpx = nwg >> 3;
  int swz = (bid & 7) * cpx + (bid >> 3);
  int bxs = swz % gridDim.x, bys = swz / gridDim.x;
  const int n0 = bxs * (NB * 64), m0 = bys * 256;

  const int t = threadIdx.x;
  const int lane = t & 63, w = t >> 6;
  const int wr = w >> 2, wc = w & 3;          // 2M x 4N waves
  const int lg = lane >> 4, lm = lane & 15;
  const int NT = K >> 6;

  f32x4 acc[8][NB] = {};
  bf16x8 aF[4], bF[2][NB];

  // ---- prologue: buf0 = K-tile 0 (A+B); buf1 B of K-tile 1 ----
  STG8(0, 0, 0, 0); STG8(0, 0, 0, 1); STG8(0, 0, 0, 2); STG8(0, 0, 0, 3);
  STG8(0, 1, 0, 0); if (NB > 1) STG8(0, 1, 0, 1); if (NB > 2) STG8(0, 1, 0, 2);
  STG8(1, 1, 1, 0); if (NB > 1) STG8(1, 1, 1, 1); if (NB > 2) STG8(1, 1, 1, 2);
  WVM(NB);
  BAR();

  for (int I = 0; I < (NT >> 1); ++I) {
    const int tt = 2 * I;
    const bool pf = (I < (NT >> 1) - 1);
    // ===== K-tile tt in buf0 =====
    // ph1
    DSA8(0, 0, 0); DSB8(0);
    STG8(1, 0, tt + 1, 0); STG8(1, 0, tt + 1, 1);
    BAR(); MM8(0, 0); BAR();
    // ph2
    DSA8(0, 1, 0);
    STG8(1, 0, tt + 1, 2); STG8(1, 0, tt + 1, 3);
    BAR(); MM8(1, 0); BAR();
    // ph3
    DSA8(0, 0, 1);
    if (pf) { STG8(0, 1, tt + 2, 0); if (NB > 1) STG8(0, 1, tt + 2, 1); }
    BAR(); MM8(0, 1); BAR();
    // ph4
    DSA8(0, 1, 1);
    if (pf) { if (NB > 2) STG8(0, 1, tt + 2, 2); }
    BAR(); MM8(1, 1);
    if (pf) WVM(NB); else WVM(0);
    BAR();
    // ===== K-tile tt+1 in buf1 =====
    // ph5
    DSA8(1, 0, 0); DSB8(1);
    if (pf) { STG8(0, 0, tt + 2, 0); STG8(0, 0, tt + 2, 1); }
    BAR(); MM8(0, 0); BAR();
    // ph6
    DSA8(1, 1, 0);
    if (pf) { STG8(0, 0, tt + 2, 2); STG8(0, 0, tt + 2, 3); }
    BAR(); MM8(1, 0); BAR();
    // ph7
    DSA8(1, 0, 1);
    if (pf) { STG8(1, 1, tt + 3, 0); if (NB > 1) STG8(1, 1, tt + 3, 1); }
    BAR(); MM8(0, 1); BAR();
    // ph8
    DSA8(1, 1, 1);
    if (pf) { if (NB > 2) STG8(1, 1, tt + 3, 2); }
    BAR(); MM8(1, 1);
    if (pf) WVM(NB); else WVM(0);
    BAR();
  }

  // ---- epilogue ----
#pragma unroll
  for (int am = 0; am < 8; ++am) {
    int row = m0 + wr * 128 + am * 16 + lg * 4;
#pragma unroll
    for (int nf = 0; nf < NB; ++nf) {
      int col = n0 + wc * (NB * 16) + nf * 16 + lm;
#pragma unroll
      for (int rr = 0; rr < 4; ++rr) {
        if constexpr (sizeof(OutT) == 4) C[(long)(row + rr) * N + col] = acc[am][nf][rr];
        else                             C[(long)(row + rr) * N + col] = (bf16)acc[am][nf][rr];
      }
    }
  }
}

// ---------------- GQA causal flash attention (R6 v6, unchanged) ----------------
__global__ __launch_bounds__(512, 4) void attn_kernel(const bf16* __restrict__ qkv,
                                                      bf16* __restrict__ out) {
  __shared__ __align__(16) bf16 Ks[2][64 * 128];
  __shared__ __align__(16) bf16 Vt[128 * PADV];

  const int bx = blockIdx.x;
  const int qt = 15 - (bx >> 5);        // heaviest q-tiles dispatch first
  const int h = bx & 31;                // head -> fixed XCD: KV L2 locality
  const int kvh = h >> 2;               // GROUPS = 4
  const int q0 = qt * 128;
  const int t = threadIdx.x, lane = t & 63, w = t >> 6;   // 8 waves
  const int lg = lane >> 4, lm = lane & 15;
  const int dchunk = t >> 5, kv2 = t & 31;
  const int kva = kv2 * 2;
  const int k5 = kva & 31;
  const int slot = ((kva >> 5) << 5) | (((k5 >> 2) & 3) << 3) | ((k5 >> 4) << 2) | (k5 & 3);
  const bf16* kbase = qkv + K_COL + kvh * HD;
  const bf16* vbase = qkv + V_COL + kvh * HD;

  const long qrow = q0 + w * 16 + lm;
  bf16x8 qf[4];
#pragma unroll
  for (int ks = 0; ks < 4; ++ks)
    qf[ks] = *reinterpret_cast<const bf16x8*>(qkv + qrow * QKV_N + h * HD + ks * 32 + lg * 8);

  f32x4 o[8];
#pragma unroll
  for (int i = 0; i < 8; ++i) o[i] = f32x4{0.f, 0.f, 0.f, 0.f};
  float mrow = -1e30f, lrow = 0.f;

  bf16x8 a0, a1;
  {
#pragma unroll
    for (int i = 0; i < 2; ++i) {
      int c = i * 512 + t;
      int r = c >> 4, jl = c & 15;
      int jg = jl ^ (r & 15);
      const bf16* src = kbase + (long)r * QKV_N + jg * 8;
      __builtin_amdgcn_global_load_lds((const __attribute__((address_space(1))) void*)src,
                                       (__attribute__((address_space(3))) void*)(Ks[0] + c * 8), 16, 0, 0);
    }
    const bf16* vs = vbase + (long)kva * QKV_N + dchunk * 8;
    a0 = *reinterpret_cast<const bf16x8*>(vs);
    a1 = *reinterpret_cast<const bf16x8*>(vs + QKV_N);
  }

  const int nst = 2 * qt + 2;
  for (int st = 0; st < nst; ++st) {
    const int cur = st & 1;
#pragma unroll
    for (int e = 0; e < 8; ++e) {
      bf16x2 pk; pk[0] = a0[e]; pk[1] = a1[e];
      *reinterpret_cast<bf16x2*>(Vt + (dchunk * 8 + e) * PADV + slot) = pk;
    }
    __syncthreads();

    if (st + 1 < nst) {
      const long kv0n = (long)(st + 1) * 64;
#pragma unroll
      for (int i = 0; i < 2; ++i) {
        int c = i * 512 + t;
        int r = c >> 4, jl = c & 15;
        int jg = jl ^ (r & 15);
        const bf16* src = kbase + (kv0n + r) * QKV_N + jg * 8;
        __builtin_amdgcn_global_load_lds((const __attribute__((address_space(1))) void*)src,
                                         (__attribute__((address_space(3))) void*)(Ks[cur ^ 1] + c * 8), 16, 0, 0);
      }
      const bf16* vs = vbase + (kv0n + kva) * QKV_N + dchunk * 8;
      a0 = *reinterpret_cast<const bf16x8*>(vs);
      a1 = *reinterpret_cast<const bf16x8*>(vs + QKV_N);
    }

    const int kv0 = st * 64;
    const int qg = q0 + w * 16 + lm;
    if (kv0 <= q0 + w * 16 + 15) {
      f32x4 s[4];
#pragma unroll
      for (int cb = 0; cb < 4; ++cb) s[cb] = f32x4{0.f, 0.f, 0.f, 0.f};
      __builtin_amdgcn_s_setprio(1);
#pragma unroll
      for (int ks = 0; ks < 4; ++ks) {
#pragma unroll
        for (int cb = 0; cb < 4; ++cb) {
          bf16x8 kf = *reinterpret_cast<const bf16x8*>(
              Ks[cur] + (cb * 16 + lm) * 128 + (((ks * 4 + lg) ^ lm) << 3));
          s[cb] = __builtin_amdgcn_mfma_f32_16x16x32_bf16(kf, qf[ks], s[cb], 0, 0, 0);
        }
      }
      __builtin_amdgcn_s_setprio(0);

      const float SC = 0.12751742f;
      float sl[4][4];
#pragma unroll
      for (int cb = 0; cb < 4; ++cb)
#pragma unroll
        for (int r = 0; r < 4; ++r) {
          float v = s[cb][r] * SC;
          if (st >= nst - 2 && (kv0 + cb * 16 + lg * 4 + r) > qg) v = -1e30f;
          sl[cb][r] = v;
        }
      float tm = sl[0][0];
#pragma unroll
      for (int cb = 0; cb < 4; ++cb)
#pragma unroll
        for (int r = 0; r < 4; ++r) tm = fmaxf(tm, sl[cb][r]);
      tm = fmaxf(tm, __shfl_xor(tm, 16));
      tm = fmaxf(tm, __shfl_xor(tm, 32));

      if (__any(tm > mrow + 8.f)) {
        float mnew = fmaxf(mrow, tm);
        float alpha = exp2f(mrow - mnew);
        mrow = mnew;
        lrow *= alpha;
        float ar[4];
#pragma unroll
        for (int r = 0; r < 4; ++r)
          ar[r] = __shfl(alpha, (lane & 48) | (lg * 4 + r));
#pragma unroll
        for (int i = 0; i < 8; ++i)
#pragma unroll
          for (int r = 0; r < 4; ++r) o[i][r] *= ar[r];
      }
      float p[4][4];
      float psum = 0.f;
#pragma unroll
      for (int cb = 0; cb < 4; ++cb)
#pragma unroll
        for (int r = 0; r < 4; ++r) {
          p[cb][r] = exp2f(sl[cb][r] - mrow);
          psum += p[cb][r];
        }
      psum += __shfl_xor(psum, 16);
      psum += __shfl_xor(psum, 32);
      lrow += psum;

      bf16x8 pa0, pa1;
#pragma unroll
      for (int r = 0; r < 4; ++r) {
        pa0[r]     = (bf16)p[0][r];
        pa0[4 + r] = (bf16)p[1][r];
        pa1[r]     = (bf16)p[2][r];
        pa1[4 + r] = (bf16)p[3][r];
      }

      __builtin_amdgcn_s_setprio(1);
#pragma unroll
      for (int db = 0; db < 8; ++db) {
        bf16x8 vf0 = *reinterpret_cast<const bf16x8*>(Vt + (db * 16 + lm) * PADV + lg * 8);
        bf16x8 vf1 = *reinterpret_cast<const bf16x8*>(Vt + (db * 16 + lm) * PADV + 32 + lg * 8);
        o[db] = __builtin_amdgcn_mfma_f32_16x16x32_bf16(pa0, vf0, o[db], 0, 0, 0);
        o[db] = __builtin_amdgcn_mfma_f32_16x16x32_bf16(pa1, vf1, o[db], 0, 0, 0);
      }
      __builtin_amdgcn_s_setprio(0);
    }

    if (st + 1 < nst) __syncthreads();
  }

  float invr[4];
#pragma unroll
  for (int r = 0; r < 4; ++r)
    invr[r] = 1.0f / __shfl(lrow, (lane & 48) | (lg * 4 + r));
#pragma unroll
  for (int r = 0; r < 4; ++r) {
    long row = q0 + w * 16 + lg * 4 + r;
#pragma unroll
    for (int db = 0; db < 8; ++db)
      out[row * HID_DIM + h * HD + db * 16 + lm] = (bf16)(o[db][r] * invr[r]);
  }
}

extern "C" void kernel_launch(void* const* d_in, const int* in_sizes, int n_in,
                              void* d_out, int out_size, void* d_ws, size_t ws_size,
                              hipStream_t stream) {
  const float* hs = (const float*)d_in[0];
  const float* Wq = (const float*)d_in[1];
  const float* Wk = (const float*)d_in[2];
  const float* Wv = (const float*)d_in[3];
  const float* Wo = (const float*)d_in[4];
  float* out = (float*)d_out;
  char* ws = (char*)d_ws;

  bf16*  hsb   = (bf16*)(ws);                    // 2048x4096 bf16
  bf16*  wqkvb = (bf16*)(ws + 16777216);         // 6144x4096 bf16
  bf16*  wob   = (bf16*)(ws + 67108864);         // 4096x4096 bf16
  bf16*  qkv   = (bf16*)(ws + 100663296);        // 2048x6144 bf16
  bf16*  attn  = (bf16*)(ws + 125829120);        // 2048x4096 bf16
  float* cost  = (float*)(ws + 142606336);       // 2048x64 f32
  float* sint  = (float*)(ws + 143130624);       // 2048x64 f32

  cvt_all_kernel<<<49152, 256, 0, stream>>>(hs, Wq, Wk, Wv, Wo, hsb, wqkvb, wob);
  rope_table_kernel<<<512, 256, 0, stream>>>(cost, sint);
  gemm8p_kernel<3, bf16><<<dim3(32, 8), 512, 0, stream>>>(hsb, wqkvb, qkv, 2048, 6144, 4096);
  rope_apply_kernel<<<2560, 256, 0, stream>>>(qkv, cost, sint);
  attn_kernel<<<512, 512, 0, stream>>>(qkv, attn);
  gemm8p_kernel<2, float><<<dim3(32, 8), 512, 0, stream>>>(attn, wob, out, 2048, 4096, 4096);
}

// Round 8
// 309.210 us; speedup vs baseline: 2.1902x; 1.0047x over previous
//
#include <hip/hip_runtime.h>

typedef __bf16 bf16;
typedef __bf16 bf16x2 __attribute__((ext_vector_type(2)));
typedef __bf16 bf16x4 __attribute__((ext_vector_type(4)));
typedef __bf16 bf16x8 __attribute__((ext_vector_type(8)));
typedef float f32x4 __attribute__((ext_vector_type(4)));

#define S_LEN 2048
#define HID_DIM 4096
#define NH 32
#define NKV 8
#define HD 128
#define QKV_N 6144   // 4096 Q + 1024 K + 1024 V
#define K_COL 4096
#define V_COL 5120
#define PADV 76

// ------- fused fp32->bf16 conversion for all 5 inputs + RoPE table gen -------
__global__ void cvt_all_kernel(const float* __restrict__ hs, const float* __restrict__ wq,
                               const float* __restrict__ wk, const float* __restrict__ wv,
                               const float* __restrict__ wo, bf16* __restrict__ hsb,
                               bf16* __restrict__ wqkvb, bf16* __restrict__ wob,
                               float* __restrict__ cost, float* __restrict__ sint) {
  long i = (long)blockIdx.x * blockDim.x + threadIdx.x;
  if (i >= 12582912) {                   // RoPE tables: 2048*64 entries
    int j = (int)(i - 12582912);
    int s = j >> 6, d = j & 63;
    float inv = expf(-0.14391156831212787f * (float)d);   // 10000^(-d/64)
    float ang = (float)s * inv;
    cost[j] = cosf(ang);
    sint[j] = sinf(ang);
    return;
  }
  const float* src; bf16* dst; long off;
  if (i < 2097152)      { src = hs; dst = hsb;                          off = i; }
  else if (i < 6291456) { src = wq; dst = wqkvb;                        off = i - 2097152; }
  else if (i < 7340032) { src = wk; dst = wqkvb + (long)4096 * 4096;    off = i - 6291456; }
  else if (i < 8388608) { src = wv; dst = wqkvb + (long)5120 * 4096;    off = i - 7340032; }
  else                  { src = wo; dst = wob;                          off = i - 8388608; }
  float4 v = reinterpret_cast<const float4*>(src)[off];
  bf16x4 o;
  o[0] = (bf16)v.x; o[1] = (bf16)v.y; o[2] = (bf16)v.z; o[3] = (bf16)v.w;
  reinterpret_cast<bf16x4*>(dst)[off] = o;
}

// ---------------- RoPE apply in-place, vectorized bf16x8 ----------------
__global__ void rope_apply_kernel(bf16* __restrict__ qkv, const float* __restrict__ cost,
                                  const float* __restrict__ sint) {
  int idx = blockIdx.x * blockDim.x + threadIdx.x;  // 2048 rows * 320 chunks
  int s = idx / 320;
  int c = idx - s * 320;
  int g = c >> 3, dc = (c & 7) * 8;
  long base = (long)s * QKV_N + g * 128 + dc;
  bf16x8 x1 = *reinterpret_cast<const bf16x8*>(qkv + base);
  bf16x8 x2 = *reinterpret_cast<const bf16x8*>(qkv + base + 64);
  const float* cp = cost + (s << 6) + dc;
  const float* sp = sint + (s << 6) + dc;
  float4 ca = *reinterpret_cast<const float4*>(cp);
  float4 cb = *reinterpret_cast<const float4*>(cp + 4);
  float4 sa = *reinterpret_cast<const float4*>(sp);
  float4 sb = *reinterpret_cast<const float4*>(sp + 4);
  float co[8] = {ca.x, ca.y, ca.z, ca.w, cb.x, cb.y, cb.z, cb.w};
  float sn[8] = {sa.x, sa.y, sa.z, sa.w, sb.x, sb.y, sb.z, sb.w};
  bf16x8 y1, y2;
#pragma unroll
  for (int e = 0; e < 8; ++e) {
    float a = (float)x1[e], b = (float)x2[e];
    y1[e] = (bf16)(a * co[e] - b * sn[e]);
    y2[e] = (bf16)(b * co[e] + a * sn[e]);
  }
  *reinterpret_cast<bf16x8*>(qkv + base)      = y1;
  *reinterpret_cast<bf16x8*>(qkv + base + 64) = y2;
}

// ---- 4-phase GEMM: BM=256, BN=NB*64, BK=64, phases=(tile,mh) halves ----
// 512 thr / 8 waves (2M x 4N); staging in 64-row units (1 gload_lds/thread);
// counted vmcnt(NB) once per K-tile; both-sides chunk-XOR swizzle.
// grid = (N/(NB*64)) x (M/256), nwg % 8 == 0. C[M,N] = A[M,K] @ B[N,K]^T.
#define STG8(buf, mat, kt, unit) {                                                       \
    const bf16* sp_ = (mat) ? Bp : Ap;                                                   \
    int row0_ = ((mat) ? n0 : m0) + (unit) * 64;                                         \
    int lb_ = (buf) * LBUF + (mat) * 16384 + (unit) * 4096;                              \
    int r_ = t >> 3, jl_ = t & 7, jg_ = jl_ ^ (r_ & 7);                                  \
    const bf16* src_ = sp_ + (long)(row0_ + r_) * K + (kt) * 64 + jg_ * 8;               \
    __builtin_amdgcn_global_load_lds((const __attribute__((address_space(1))) void*)src_,\
        (__attribute__((address_space(3))) void*)(L + lb_ + t * 8), 16, 0, 0); }

#define DSA2(buf, mh) {                                                                  \
    _Pragma("unroll") for (int ks_ = 0; ks_ < 2; ++ks_)                                  \
      _Pragma("unroll") for (int mf_ = 0; mf_ < 4; ++mf_) {                              \
        int R_ = wr * 128 + (mh) * 64 + mf_ * 16 + lm;                                   \
        aF[ks_][mf_] = *reinterpret_cast<const bf16x8*>(                                 \
            L + (buf) * LBUF + R_ * 64 + (((ks_ * 4 + lg) ^ (R_ & 7)) << 3));            \
      } }

#define DSBALL(buf) {                                                                    \
    _Pragma("unroll") for (int ks_ = 0; ks_ < 2; ++ks_)                                  \
      _Pragma("unroll") for (int nf_ = 0; nf_ < NB; ++nf_) {                             \
        int R_ = wc * (NB * 16) + nf_ * 16 + lm;                                         \
        bF[ks_][nf_] = *reinterpret_cast<const bf16x8*>(                                 \
            L + (buf) * LBUF + 16384 + R_ * 64 + (((ks_ * 4 + lg) ^ (R_ & 7)) << 3));    \
      } }

#define MM2(mh) {                                                                        \
    __builtin_amdgcn_s_setprio(1);                                                       \
    _Pragma("unroll") for (int mf_ = 0; mf_ < 4; ++mf_)                                  \
      _Pragma("unroll") for (int nf_ = 0; nf_ < NB; ++nf_)                               \
        _Pragma("unroll") for (int ks_ = 0; ks_ < 2; ++ks_)                              \
          acc[(mh) * 4 + mf_][nf_] = __builtin_amdgcn_mfma_f32_16x16x32_bf16(            \
              aF[ks_][mf_], bF[ks_][nf_], acc[(mh) * 4 + mf_][nf_], 0, 0, 0);            \
    __builtin_amdgcn_s_setprio(0); }

#define BAR() __builtin_amdgcn_s_barrier()
#define WVM(n) asm volatile("s_waitcnt vmcnt(%0)" :: "i"(n) : "memory")

template<int NB, typename OutT>
__global__ __launch_bounds__(512, 1) void gemm4p_kernel(
    const bf16* __restrict__ Ap, const bf16* __restrict__ Bp, OutT* __restrict__ C,
    int M, int N, int K) {
  constexpr int LBUF = 16384 + NB * 4096;     // bf16 elems per K-tile buffer
  __shared__ __align__(16) bf16 L[2 * LBUF];

  int nwg = gridDim.x * gridDim.y;
  int bid = blockIdx.y * gridDim.x + blockIdx.x;
  int cpx = nwg >> 3;
  int swz = (bid & 7) * cpx + (bid >> 3);
  int bxs = swz % gridDim.x, bys = swz / gridDim.x;
  const int n0 = bxs * (NB * 64), m0 = bys * 256;

  const int t = threadIdx.x;
  const int lane = t & 63, w = t >> 6;
  const int wr = w >> 2, wc = w & 3;          // 2M x 4N waves
  const int lg = lane >> 4, lm = lane & 15;
  const int NT = K >> 6;

  f32x4 acc[8][NB] = {};
  bf16x8 aF[2][4], bF[2][NB];

  // ---- prologue: buf0 = K-tile 0 (A+B); buf1 = B of K-tile 1 ----
  STG8(0, 0, 0, 0); STG8(0, 0, 0, 1); STG8(0, 0, 0, 2); STG8(0, 0, 0, 3);
  STG8(0, 1, 0, 0); if (NB > 1) STG8(0, 1, 0, 1); if (NB > 2) STG8(0, 1, 0, 2);
  STG8(1, 1, 1, 0); if (NB > 1) STG8(1, 1, 1, 1); if (NB > 2) STG8(1, 1, 1, 2);
  WVM(NB);
  BAR();

  for (int I = 0; I < (NT >> 1); ++I) {
    const int tt = 2 * I;
    const bool pf = (I < (NT >> 1) - 1);
    // ===== K-tile tt in buf0 =====
    // phA: reads buf0 A(mh0)+B(all); stages A(tt+1)->buf1
    DSA2(0, 0); DSBALL(0);
    STG8(1, 0, tt + 1, 0); STG8(1, 0, tt + 1, 1);
    STG8(1, 0, tt + 1, 2); STG8(1, 0, tt + 1, 3);
    BAR(); MM2(0); BAR();
    // phB: reads buf0 A(mh1); stages B(tt+2)->buf0
    DSA2(0, 1);
    if (pf) { STG8(0, 1, tt + 2, 0); if (NB > 1) STG8(0, 1, tt + 2, 1);
              if (NB > 2) STG8(0, 1, tt + 2, 2); }
    BAR(); MM2(1);
    if (pf) WVM(NB); else WVM(0);
    BAR();
    // ===== K-tile tt+1 in buf1 =====
    // phC: reads buf1 A(mh0)+B(all); stages A(tt+2)->buf0
    DSA2(1, 0); DSBALL(1);
    if (pf) { STG8(0, 0, tt + 2, 0); STG8(0, 0, tt + 2, 1);
              STG8(0, 0, tt + 2, 2); STG8(0, 0, tt + 2, 3); }
    BAR(); MM2(0); BAR();
    // phD: reads buf1 A(mh1); stages B(tt+3)->buf1
    DSA2(1, 1);
    if (pf) { STG8(1, 1, tt + 3, 0); if (NB > 1) STG8(1, 1, tt + 3, 1);
              if (NB > 2) STG8(1, 1, tt + 3, 2); }
    BAR(); MM2(1);
    if (pf) WVM(NB); else WVM(0);
    BAR();
  }

  // ---- epilogue ----
#pragma unroll
  for (int am = 0; am < 8; ++am) {
    int row = m0 + wr * 128 + am * 16 + lg * 4;
#pragma unroll
    for (int nf = 0; nf < NB; ++nf) {
      int col = n0 + wc * (NB * 16) + nf * 16 + lm;
#pragma unroll
      for (int rr = 0; rr < 4; ++rr) {
        if constexpr (sizeof(OutT) == 4) C[(long)(row + rr) * N + col] = acc[am][nf][rr];
        else                             C[(long)(row + rr) * N + col] = (bf16)acc[am][nf][rr];
      }
    }
  }
}

// ---------------- GQA causal flash attention (R6 v6, unchanged) ----------------
__global__ __launch_bounds__(512, 4) void attn_kernel(const bf16* __restrict__ qkv,
                                                      bf16* __restrict__ out) {
  __shared__ __align__(16) bf16 Ks[2][64 * 128];
  __shared__ __align__(16) bf16 Vt[128 * PADV];

  const int bx = blockIdx.x;
  const int qt = 15 - (bx >> 5);        // heaviest q-tiles dispatch first
  const int h = bx & 31;                // head -> fixed XCD: KV L2 locality
  const int kvh = h >> 2;               // GROUPS = 4
  const int q0 = qt * 128;
  const int t = threadIdx.x, lane = t & 63, w = t >> 6;   // 8 waves
  const int lg = lane >> 4, lm = lane & 15;
  const int dchunk = t >> 5, kv2 = t & 31;
  const int kva = kv2 * 2;
  const int k5 = kva & 31;
  const int slot = ((kva >> 5) << 5) | (((k5 >> 2) & 3) << 3) | ((k5 >> 4) << 2) | (k5 & 3);
  const bf16* kbase = qkv + K_COL + kvh * HD;
  const bf16* vbase = qkv + V_COL + kvh * HD;

  const long qrow = q0 + w * 16 + lm;
  bf16x8 qf[4];
#pragma unroll
  for (int ks = 0; ks < 4; ++ks)
    qf[ks] = *reinterpret_cast<const bf16x8*>(qkv + qrow * QKV_N + h * HD + ks * 32 + lg * 8);

  f32x4 o[8];
#pragma unroll
  for (int i = 0; i < 8; ++i) o[i] = f32x4{0.f, 0.f, 0.f, 0.f};
  float mrow = -1e30f, lrow = 0.f;

  bf16x8 a0, a1;
  {
#pragma unroll
    for (int i = 0; i < 2; ++i) {
      int c = i * 512 + t;
      int r = c >> 4, jl = c & 15;
      int jg = jl ^ (r & 15);
      const bf16* src = kbase + (long)r * QKV_N + jg * 8;
      __builtin_amdgcn_global_load_lds((const __attribute__((address_space(1))) void*)src,
                                       (__attribute__((address_space(3))) void*)(Ks[0] + c * 8), 16, 0, 0);
    }
    const bf16* vs = vbase + (long)kva * QKV_N + dchunk * 8;
    a0 = *reinterpret_cast<const bf16x8*>(vs);
    a1 = *reinterpret_cast<const bf16x8*>(vs + QKV_N);
  }

  const int nst = 2 * qt + 2;
  for (int st = 0; st < nst; ++st) {
    const int cur = st & 1;
#pragma unroll
    for (int e = 0; e < 8; ++e) {
      bf16x2 pk; pk[0] = a0[e]; pk[1] = a1[e];
      *reinterpret_cast<bf16x2*>(Vt + (dchunk * 8 + e) * PADV + slot) = pk;
    }
    __syncthreads();

    if (st + 1 < nst) {
      const long kv0n = (long)(st + 1) * 64;
#pragma unroll
      for (int i = 0; i < 2; ++i) {
        int c = i * 512 + t;
        int r = c >> 4, jl = c & 15;
        int jg = jl ^ (r & 15);
        const bf16* src = kbase + (kv0n + r) * QKV_N + jg * 8;
        __builtin_amdgcn_global_load_lds((const __attribute__((address_space(1))) void*)src,
                                         (__attribute__((address_space(3))) void*)(Ks[cur ^ 1] + c * 8), 16, 0, 0);
      }
      const bf16* vs = vbase + (kv0n + kva) * QKV_N + dchunk * 8;
      a0 = *reinterpret_cast<const bf16x8*>(vs);
      a1 = *reinterpret_cast<const bf16x8*>(vs + QKV_N);
    }

    const int kv0 = st * 64;
    const int qg = q0 + w * 16 + lm;
    if (kv0 <= q0 + w * 16 + 15) {
      f32x4 s[4];
#pragma unroll
      for (int cb = 0; cb < 4; ++cb) s[cb] = f32x4{0.f, 0.f, 0.f, 0.f};
      __builtin_amdgcn_s_setprio(1);
#pragma unroll
      for (int ks = 0; ks < 4; ++ks) {
#pragma unroll
        for (int cb = 0; cb < 4; ++cb) {
          bf16x8 kf = *reinterpret_cast<const bf16x8*>(
              Ks[cur] + (cb * 16 + lm) * 128 + (((ks * 4 + lg) ^ lm) << 3));
          s[cb] = __builtin_amdgcn_mfma_f32_16x16x32_bf16(kf, qf[ks], s[cb], 0, 0, 0);
        }
      }
      __builtin_amdgcn_s_setprio(0);

      const float SC = 0.12751742f;
      float sl[4][4];
#pragma unroll
      for (int cb = 0; cb < 4; ++cb)
#pragma unroll
        for (int r = 0; r < 4; ++r) {
          float v = s[cb][r] * SC;
          if (st >= nst - 2 && (kv0 + cb * 16 + lg * 4 + r) > qg) v = -1e30f;
          sl[cb][r] = v;
        }
      float tm = sl[0][0];
#pragma unroll
      for (int cb = 0; cb < 4; ++cb)
#pragma unroll
        for (int r = 0; r < 4; ++r) tm = fmaxf(tm, sl[cb][r]);
      tm = fmaxf(tm, __shfl_xor(tm, 16));
      tm = fmaxf(tm, __shfl_xor(tm, 32));

      if (__any(tm > mrow + 8.f)) {
        float mnew = fmaxf(mrow, tm);
        float alpha = exp2f(mrow - mnew);
        mrow = mnew;
        lrow *= alpha;
        float ar[4];
#pragma unroll
        for (int r = 0; r < 4; ++r)
          ar[r] = __shfl(alpha, (lane & 48) | (lg * 4 + r));
#pragma unroll
        for (int i = 0; i < 8; ++i)
#pragma unroll
          for (int r = 0; r < 4; ++r) o[i][r] *= ar[r];
      }
      float p[4][4];
      float psum = 0.f;
#pragma unroll
      for (int cb = 0; cb < 4; ++cb)
#pragma unroll
        for (int r = 0; r < 4; ++r) {
          p[cb][r] = exp2f(sl[cb][r] - mrow);
          psum += p[cb][r];
        }
      psum += __shfl_xor(psum, 16);
      psum += __shfl_xor(psum, 32);
      lrow += psum;

      bf16x8 pa0, pa1;
#pragma unroll
      for (int r = 0; r < 4; ++r) {
        pa0[r]     = (bf16)p[0][r];
        pa0[4 + r] = (bf16)p[1][r];
        pa1[r]     = (bf16)p[2][r];
        pa1[4 + r] = (bf16)p[3][r];
      }

      __builtin_amdgcn_s_setprio(1);
#pragma unroll
      for (int db = 0; db < 8; ++db) {
        bf16x8 vf0 = *reinterpret_cast<const bf16x8*>(Vt + (db * 16 + lm) * PADV + lg * 8);
        bf16x8 vf1 = *reinterpret_cast<const bf16x8*>(Vt + (db * 16 + lm) * PADV + 32 + lg * 8);
        o[db] = __builtin_amdgcn_mfma_f32_16x16x32_bf16(pa0, vf0, o[db], 0, 0, 0);
        o[db] = __builtin_amdgcn_mfma_f32_16x16x32_bf16(pa1, vf1, o[db], 0, 0, 0);
      }
      __builtin_amdgcn_s_setprio(0);
    }

    if (st + 1 < nst) __syncthreads();
  }

  float invr[4];
#pragma unroll
  for (int r = 0; r < 4; ++r)
    invr[r] = 1.0f / __shfl(lrow, (lane & 48) | (lg * 4 + r));
#pragma unroll
  for (int r = 0; r < 4; ++r) {
    long row = q0 + w * 16 + lg * 4 + r;
#pragma unroll
    for (int db = 0; db < 8; ++db)
      out[row * HID_DIM + h * HD + db * 16 + lm] = (bf16)(o[db][r] * invr[r]);
  }
}

extern "C" void kernel_launch(void* const* d_in, const int* in_sizes, int n_in,
                              void* d_out, int out_size, void* d_ws, size_t ws_size,
                              hipStream_t stream) {
  const float* hs = (const float*)d_in[0];
  const float* Wq = (const float*)d_in[1];
  const float* Wk = (const float*)d_in[2];
  const float* Wv = (const float*)d_in[3];
  const float* Wo = (const float*)d_in[4];
  float* out = (float*)d_out;
  char* ws = (char*)d_ws;

  bf16*  hsb   = (bf16*)(ws);                    // 2048x4096 bf16
  bf16*  wqkvb = (bf16*)(ws + 16777216);         // 6144x4096 bf16
  bf16*  wob   = (bf16*)(ws + 67108864);         // 4096x4096 bf16
  bf16*  qkv   = (bf16*)(ws + 100663296);        // 2048x6144 bf16
  bf16*  attn  = (bf16*)(ws + 125829120);        // 2048x4096 bf16
  float* cost  = (float*)(ws + 142606336);       // 2048x64 f32
  float* sint  = (float*)(ws + 143130624);       // 2048x64 f32

  cvt_all_kernel<<<49664, 256, 0, stream>>>(hs, Wq, Wk, Wv, Wo, hsb, wqkvb, wob, cost, sint);
  gemm4p_kernel<3, bf16><<<dim3(32, 8), 512, 0, stream>>>(hsb, wqkvb, qkv, 2048, 6144, 4096);
  rope_apply_kernel<<<2560, 256, 0, stream>>>(qkv, cost, sint);
  attn_kernel<<<512, 512, 0, stream>>>(qkv, attn);
  gemm4p_kernel<2, float><<<dim3(32, 8), 512, 0, stream>>>(attn, wob, out, 2048, 4096, 4096);
}

// Round 9
// 302.483 us; speedup vs baseline: 2.2389x; 1.0222x over previous
//
#include <hip/hip_runtime.h>

typedef __bf16 bf16;
typedef __bf16 bf16x2 __attribute__((ext_vector_type(2)));
typedef __bf16 bf16x4 __attribute__((ext_vector_type(4)));
typedef __bf16 bf16x8 __attribute__((ext_vector_type(8)));
typedef float f32x4 __attribute__((ext_vector_type(4)));

#define S_LEN 2048
#define HID_DIM 4096
#define NH 32
#define NKV 8
#define HD 128
#define QKV_N 6144   // 4096 Q + 1024 K + 1024 V
#define K_COL 4096
#define V_COL 5120
#define PADV 76

// ------- fused fp32->bf16 conversion for all 5 inputs + RoPE table gen -------
__global__ void cvt_all_kernel(const float* __restrict__ hs, const float* __restrict__ wq,
                               const float* __restrict__ wk, const float* __restrict__ wv,
                               const float* __restrict__ wo, bf16* __restrict__ hsb,
                               bf16* __restrict__ wqkvb, bf16* __restrict__ wob,
                               float* __restrict__ cost, float* __restrict__ sint) {
  long i = (long)blockIdx.x * blockDim.x + threadIdx.x;
  if (i >= 12582912) {                   // RoPE tables: 2048*64 entries
    int j = (int)(i - 12582912);
    int s = j >> 6, d = j & 63;
    float inv = expf(-0.14391156831212787f * (float)d);   // 10000^(-d/64)
    float ang = (float)s * inv;
    cost[j] = cosf(ang);
    sint[j] = sinf(ang);
    return;
  }
  const float* src; bf16* dst; long off;
  if (i < 2097152)      { src = hs; dst = hsb;                          off = i; }
  else if (i < 6291456) { src = wq; dst = wqkvb;                        off = i - 2097152; }
  else if (i < 7340032) { src = wk; dst = wqkvb + (long)4096 * 4096;    off = i - 6291456; }
  else if (i < 8388608) { src = wv; dst = wqkvb + (long)5120 * 4096;    off = i - 7340032; }
  else                  { src = wo; dst = wob;                          off = i - 8388608; }
  float4 v = reinterpret_cast<const float4*>(src)[off];
  bf16x4 o;
  o[0] = (bf16)v.x; o[1] = (bf16)v.y; o[2] = (bf16)v.z; o[3] = (bf16)v.w;
  reinterpret_cast<bf16x4*>(dst)[off] = o;
}

// ---------------- RoPE apply in-place, vectorized bf16x8 ----------------
__global__ void rope_apply_kernel(bf16* __restrict__ qkv, const float* __restrict__ cost,
                                  const float* __restrict__ sint) {
  int idx = blockIdx.x * blockDim.x + threadIdx.x;  // 2048 rows * 320 chunks
  int s = idx / 320;
  int c = idx - s * 320;
  int g = c >> 3, dc = (c & 7) * 8;
  long base = (long)s * QKV_N + g * 128 + dc;
  bf16x8 x1 = *reinterpret_cast<const bf16x8*>(qkv + base);
  bf16x8 x2 = *reinterpret_cast<const bf16x8*>(qkv + base + 64);
  const float* cp = cost + (s << 6) + dc;
  const float* sp = sint + (s << 6) + dc;
  float4 ca = *reinterpret_cast<const float4*>(cp);
  float4 cb = *reinterpret_cast<const float4*>(cp + 4);
  float4 sa = *reinterpret_cast<const float4*>(sp);
  float4 sb = *reinterpret_cast<const float4*>(sp + 4);
  float co[8] = {ca.x, ca.y, ca.z, ca.w, cb.x, cb.y, cb.z, cb.w};
  float sn[8] = {sa.x, sa.y, sa.z, sa.w, sb.x, sb.y, sb.z, sb.w};
  bf16x8 y1, y2;
#pragma unroll
  for (int e = 0; e < 8; ++e) {
    float a = (float)x1[e], b = (float)x2[e];
    y1[e] = (bf16)(a * co[e] - b * sn[e]);
    y2[e] = (bf16)(b * co[e] + a * sn[e]);
  }
  *reinterpret_cast<bf16x8*>(qkv + base)      = y1;
  *reinterpret_cast<bf16x8*>(qkv + base + 64) = y2;
}

// ---- 4-phase GEMM: BM=256, BN=NB*64, BK=64 (R8, unchanged) ----
#define STG8(buf, mat, kt, unit) {                                                       \
    const bf16* sp_ = (mat) ? Bp : Ap;                                                   \
    int row0_ = ((mat) ? n0 : m0) + (unit) * 64;                                         \
    int lb_ = (buf) * LBUF + (mat) * 16384 + (unit) * 4096;                              \
    int r_ = t >> 3, jl_ = t & 7, jg_ = jl_ ^ (r_ & 7);                                  \
    const bf16* src_ = sp_ + (long)(row0_ + r_) * K + (kt) * 64 + jg_ * 8;               \
    __builtin_amdgcn_global_load_lds((const __attribute__((address_space(1))) void*)src_,\
        (__attribute__((address_space(3))) void*)(L + lb_ + t * 8), 16, 0, 0); }

#define DSA2(buf, mh) {                                                                  \
    _Pragma("unroll") for (int ks_ = 0; ks_ < 2; ++ks_)                                  \
      _Pragma("unroll") for (int mf_ = 0; mf_ < 4; ++mf_) {                              \
        int R_ = wr * 128 + (mh) * 64 + mf_ * 16 + lm;                                   \
        aF[ks_][mf_] = *reinterpret_cast<const bf16x8*>(                                 \
            L + (buf) * LBUF + R_ * 64 + (((ks_ * 4 + lg) ^ (R_ & 7)) << 3));            \
      } }

#define DSBALL(buf) {                                                                    \
    _Pragma("unroll") for (int ks_ = 0; ks_ < 2; ++ks_)                                  \
      _Pragma("unroll") for (int nf_ = 0; nf_ < NB; ++nf_) {                             \
        int R_ = wc * (NB * 16) + nf_ * 16 + lm;                                         \
        bF[ks_][nf_] = *reinterpret_cast<const bf16x8*>(                                 \
            L + (buf) * LBUF + 16384 + R_ * 64 + (((ks_ * 4 + lg) ^ (R_ & 7)) << 3));    \
      } }

#define MM2(mh) {                                                                        \
    __builtin_amdgcn_s_setprio(1);                                                       \
    _Pragma("unroll") for (int mf_ = 0; mf_ < 4; ++mf_)                                  \
      _Pragma("unroll") for (int nf_ = 0; nf_ < NB; ++nf_)                               \
        _Pragma("unroll") for (int ks_ = 0; ks_ < 2; ++ks_)                              \
          acc[(mh) * 4 + mf_][nf_] = __builtin_amdgcn_mfma_f32_16x16x32_bf16(            \
              aF[ks_][mf_], bF[ks_][nf_], acc[(mh) * 4 + mf_][nf_], 0, 0, 0);            \
    __builtin_amdgcn_s_setprio(0); }

#define BAR() __builtin_amdgcn_s_barrier()
#define WVM(n) asm volatile("s_waitcnt vmcnt(%0)" :: "i"(n) : "memory")

template<int NB, typename OutT>
__global__ __launch_bounds__(512, 1) void gemm4p_kernel(
    const bf16* __restrict__ Ap, const bf16* __restrict__ Bp, OutT* __restrict__ C,
    int M, int N, int K) {
  constexpr int LBUF = 16384 + NB * 4096;     // bf16 elems per K-tile buffer
  __shared__ __align__(16) bf16 L[2 * LBUF];

  int nwg = gridDim.x * gridDim.y;
  int bid = blockIdx.y * gridDim.x + blockIdx.x;
  int cpx = nwg >> 3;
  int swz = (bid & 7) * cpx + (bid >> 3);
  int bxs = swz % gridDim.x, bys = swz / gridDim.x;
  const int n0 = bxs * (NB * 64), m0 = bys * 256;

  const int t = threadIdx.x;
  const int lane = t & 63, w = t >> 6;
  const int wr = w >> 2, wc = w & 3;          // 2M x 4N waves
  const int lg = lane >> 4, lm = lane & 15;
  const int NT = K >> 6;

  f32x4 acc[8][NB] = {};
  bf16x8 aF[2][4], bF[2][NB];

  STG8(0, 0, 0, 0); STG8(0, 0, 0, 1); STG8(0, 0, 0, 2); STG8(0, 0, 0, 3);
  STG8(0, 1, 0, 0); if (NB > 1) STG8(0, 1, 0, 1); if (NB > 2) STG8(0, 1, 0, 2);
  STG8(1, 1, 1, 0); if (NB > 1) STG8(1, 1, 1, 1); if (NB > 2) STG8(1, 1, 1, 2);
  WVM(NB);
  BAR();

  for (int I = 0; I < (NT >> 1); ++I) {
    const int tt = 2 * I;
    const bool pf = (I < (NT >> 1) - 1);
    DSA2(0, 0); DSBALL(0);
    STG8(1, 0, tt + 1, 0); STG8(1, 0, tt + 1, 1);
    STG8(1, 0, tt + 1, 2); STG8(1, 0, tt + 1, 3);
    BAR(); MM2(0); BAR();
    DSA2(0, 1);
    if (pf) { STG8(0, 1, tt + 2, 0); if (NB > 1) STG8(0, 1, tt + 2, 1);
              if (NB > 2) STG8(0, 1, tt + 2, 2); }
    BAR(); MM2(1);
    if (pf) WVM(NB); else WVM(0);
    BAR();
    DSA2(1, 0); DSBALL(1);
    if (pf) { STG8(0, 0, tt + 2, 0); STG8(0, 0, tt + 2, 1);
              STG8(0, 0, tt + 2, 2); STG8(0, 0, tt + 2, 3); }
    BAR(); MM2(0); BAR();
    DSA2(1, 1);
    if (pf) { STG8(1, 1, tt + 3, 0); if (NB > 1) STG8(1, 1, tt + 3, 1);
              if (NB > 2) STG8(1, 1, tt + 3, 2); }
    BAR(); MM2(1);
    if (pf) WVM(NB); else WVM(0);
    BAR();
  }

#pragma unroll
  for (int am = 0; am < 8; ++am) {
    int row = m0 + wr * 128 + am * 16 + lg * 4;
#pragma unroll
    for (int nf = 0; nf < NB; ++nf) {
      int col = n0 + wc * (NB * 16) + nf * 16 + lm;
#pragma unroll
      for (int rr = 0; rr < 4; ++rr) {
        if constexpr (sizeof(OutT) == 4) C[(long)(row + rr) * N + col] = acc[am][nf][rr];
        else                             C[(long)(row + rr) * N + col] = (bf16)acc[am][nf][rr];
      }
    }
  }
}

// ---------------- GQA causal flash attention, v7 ----------------
// v6 structure + counted-vmcnt pipeline (T4): raw s_barrier with lgkmcnt(0) only;
// exactly 4 loads (next V + next K) stay in flight across every barrier; K prefetch
// depth = 2 steps. 2-step unrolled loop with static V-reg double buffer.
#define AK_LBAR() { asm volatile("s_waitcnt lgkmcnt(0)" ::: "memory");                   \
                    __builtin_amdgcn_s_barrier(); }
#define AK_VBAR() { asm volatile("s_waitcnt vmcnt(4)" ::: "memory");                     \
                    __builtin_amdgcn_sched_barrier(0);                                   \
                    asm volatile("s_waitcnt lgkmcnt(0)" ::: "memory");                   \
                    __builtin_amdgcn_s_barrier(); }

#define AK_WRITEV(r0, r1) {                                                              \
    _Pragma("unroll") for (int e = 0; e < 8; ++e) {                                      \
      bf16x2 pk; pk[0] = r0[e]; pk[1] = r1[e];                                           \
      *reinterpret_cast<bf16x2*>(Vt + (dchunk * 8 + e) * PADV + slot) = pk;              \
    } }

#define AK_ISSUEV(base, r0, r1) {                                                        \
    long rv_ = (long)(base) + kva; if (rv_ > 2046) rv_ = 2046;                           \
    const bf16* vs_ = vbase + rv_ * QKV_N + dchunk * 8;                                  \
    r0 = *reinterpret_cast<const bf16x8*>(vs_);                                          \
    r1 = *reinterpret_cast<const bf16x8*>(vs_ + QKV_N); }

#define AK_ISSUEK(base, buf) {                                                           \
    _Pragma("unroll") for (int i_ = 0; i_ < 2; ++i_) {                                   \
      int c_ = i_ * 512 + t;                                                             \
      int r_ = c_ >> 4, jl_ = c_ & 15, jg_ = jl_ ^ (r_ & 15);                            \
      long rk_ = (long)(base) + r_; if (rk_ > 2047) rk_ = 2047;                          \
      const bf16* src_ = kbase + rk_ * QKV_N + jg_ * 8;                                  \
      __builtin_amdgcn_global_load_lds((const __attribute__((address_space(1))) void*)src_,\
          (__attribute__((address_space(3))) void*)(Ks[buf] + c_ * 8), 16, 0, 0);        \
    } }

#define AK_STEP(stv, ksb) {                                                              \
    const int st_ = (stv);                                                               \
    const int kv0_ = st_ * 64;                                                           \
    if (kv0_ <= q0 + w * 16 + 15) {                                                      \
      f32x4 s[4];                                                                        \
      _Pragma("unroll") for (int cb = 0; cb < 4; ++cb) s[cb] = f32x4{0.f,0.f,0.f,0.f};   \
      __builtin_amdgcn_s_setprio(1);                                                     \
      _Pragma("unroll") for (int ks = 0; ks < 4; ++ks)                                   \
        _Pragma("unroll") for (int cb = 0; cb < 4; ++cb) {                               \
          bf16x8 kf = *reinterpret_cast<const bf16x8*>(                                  \
              Ks[ksb] + (cb * 16 + lm) * 128 + (((ks * 4 + lg) ^ lm) << 3));             \
          s[cb] = __builtin_amdgcn_mfma_f32_16x16x32_bf16(kf, qf[ks], s[cb], 0, 0, 0);   \
        }                                                                                \
      __builtin_amdgcn_s_setprio(0);                                                     \
      const float SC = 0.12751742f;                                                      \
      float sl[4][4];                                                                    \
      _Pragma("unroll") for (int cb = 0; cb < 4; ++cb)                                   \
        _Pragma("unroll") for (int r = 0; r < 4; ++r) {                                  \
          float v = s[cb][r] * SC;                                                       \
          if (st_ >= nst - 2 && (kv0_ + cb * 16 + lg * 4 + r) > qg) v = -1e30f;          \
          sl[cb][r] = v;                                                                 \
        }                                                                                \
      float tm = sl[0][0];                                                               \
      _Pragma("unroll") for (int cb = 0; cb < 4; ++cb)                                   \
        _Pragma("unroll") for (int r = 0; r < 4; ++r) tm = fmaxf(tm, sl[cb][r]);         \
      tm = fmaxf(tm, __shfl_xor(tm, 16));                                                \
      tm = fmaxf(tm, __shfl_xor(tm, 32));                                                \
      if (__any(tm > mrow + 8.f)) {                                                      \
        float mnew = fmaxf(mrow, tm);                                                    \
        float alpha = exp2f(mrow - mnew);                                                \
        mrow = mnew; lrow *= alpha;                                                      \
        float ar[4];                                                                     \
        _Pragma("unroll") for (int r = 0; r < 4; ++r)                                    \
          ar[r] = __shfl(alpha, (lane & 48) | (lg * 4 + r));                             \
        _Pragma("unroll") for (int i = 0; i < 8; ++i)                                    \
          _Pragma("unroll") for (int r = 0; r < 4; ++r) o[i][r] *= ar[r];                \
      }                                                                                  \
      float p[4][4]; float psum = 0.f;                                                   \
      _Pragma("unroll") for (int cb = 0; cb < 4; ++cb)                                   \
        _Pragma("unroll") for (int r = 0; r < 4; ++r) {                                  \
          p[cb][r] = exp2f(sl[cb][r] - mrow); psum += p[cb][r];                          \
        }                                                                                \
      psum += __shfl_xor(psum, 16);                                                      \
      psum += __shfl_xor(psum, 32);                                                      \
      lrow += psum;                                                                      \
      bf16x8 pa0, pa1;                                                                   \
      _Pragma("unroll") for (int r = 0; r < 4; ++r) {                                    \
        pa0[r] = (bf16)p[0][r]; pa0[4 + r] = (bf16)p[1][r];                              \
        pa1[r] = (bf16)p[2][r]; pa1[4 + r] = (bf16)p[3][r];                              \
      }                                                                                  \
      __builtin_amdgcn_s_setprio(1);                                                     \
      _Pragma("unroll") for (int db = 0; db < 8; ++db) {                                 \
        bf16x8 vf0 = *reinterpret_cast<const bf16x8*>(Vt + (db*16+lm)*PADV + lg*8);      \
        bf16x8 vf1 = *reinterpret_cast<const bf16x8*>(Vt + (db*16+lm)*PADV + 32 + lg*8); \
        o[db] = __builtin_amdgcn_mfma_f32_16x16x32_bf16(pa0, vf0, o[db], 0, 0, 0);       \
        o[db] = __builtin_amdgcn_mfma_f32_16x16x32_bf16(pa1, vf1, o[db], 0, 0, 0);       \
      }                                                                                  \
      __builtin_amdgcn_s_setprio(0);                                                     \
    } }

__global__ __launch_bounds__(512, 4) void attn_kernel(const bf16* __restrict__ qkv,
                                                      bf16* __restrict__ out) {
  __shared__ __align__(16) bf16 Ks[2][64 * 128];
  __shared__ __align__(16) bf16 Vt[128 * PADV];

  const int bx = blockIdx.x;
  const int qt = 15 - (bx >> 5);        // heaviest q-tiles dispatch first
  const int h = bx & 31;                // head -> fixed XCD: KV L2 locality
  const int kvh = h >> 2;               // GROUPS = 4
  const int q0 = qt * 128;
  const int t = threadIdx.x, lane = t & 63, w = t >> 6;   // 8 waves
  const int lg = lane >> 4, lm = lane & 15;
  const int dchunk = t >> 5, kv2 = t & 31;
  const int kva = kv2 * 2;
  const int k5 = kva & 31;
  const int slot = ((kva >> 5) << 5) | (((k5 >> 2) & 3) << 3) | ((k5 >> 4) << 2) | (k5 & 3);
  const bf16* kbase = qkv + K_COL + kvh * HD;
  const bf16* vbase = qkv + V_COL + kvh * HD;

  const long qrow = q0 + w * 16 + lm;
  const int qg = q0 + w * 16 + lm;
  bf16x8 qf[4];
#pragma unroll
  for (int ks = 0; ks < 4; ++ks)
    qf[ks] = *reinterpret_cast<const bf16x8*>(qkv + qrow * QKV_N + h * HD + ks * 32 + lg * 8);

  f32x4 o[8];
#pragma unroll
  for (int i = 0; i < 8; ++i) o[i] = f32x4{0.f, 0.f, 0.f, 0.f};
  float mrow = -1e30f, lrow = 0.f;

  const int nst = 2 * qt + 2;
  bf16x8 va0, va1, vb0, vb1;

  // ---- prologue: V(0), K(0)->Ks[0], V(1), K(1)->Ks[1]; Vt=V(0) ----
  AK_ISSUEV(0, va0, va1);
  AK_ISSUEK(0, 0);
  AK_ISSUEV(64, vb0, vb1);
  AK_ISSUEK(64, 1);
  AK_WRITEV(va0, va1);        // compiler waits vA only (vmcnt leaves K0,vB,K1)
  AK_VBAR();                  // K(0) landed; vB+K(1) stay in flight

  for (int I = 0; I < (nst >> 1); ++I) {
    const int s0 = 2 * I;
    // ---- step s0 from Ks[0], Vt=V(s0) ----
    AK_STEP(s0, 0);
    AK_LBAR();                           // reads of Ks[0], Vt complete
    AK_WRITEV(vb0, vb1);                 // Vt = V(s0+1); K(s0+1) stays in flight
    AK_ISSUEV((s0 + 2) * 64, va0, va1);
    AK_ISSUEK((s0 + 2) * 64, 0);
    AK_VBAR();                           // K(s0+1) landed; vA+K(s0+2) in flight
    // ---- step s0+1 from Ks[1], Vt=V(s0+1) ----
    AK_STEP(s0 + 1, 1);
    AK_LBAR();
    AK_WRITEV(va0, va1);                 // Vt = V(s0+2)
    AK_ISSUEV((s0 + 3) * 64, vb0, vb1);
    AK_ISSUEK((s0 + 3) * 64, 1);
    AK_VBAR();                           // K(s0+2) landed
  }

  // ---- epilogue: normalize + store bf16 [S][4096] ----
  float invr[4];
#pragma unroll
  for (int r = 0; r < 4; ++r)
    invr[r] = 1.0f / __shfl(lrow, (lane & 48) | (lg * 4 + r));
#pragma unroll
  for (int r = 0; r < 4; ++r) {
    long row = q0 + w * 16 + lg * 4 + r;
#pragma unroll
    for (int db = 0; db < 8; ++db)
      out[row * HID_DIM + h * HD + db * 16 + lm] = (bf16)(o[db][r] * invr[r]);
  }
}

extern "C" void kernel_launch(void* const* d_in, const int* in_sizes, int n_in,
                              void* d_out, int out_size, void* d_ws, size_t ws_size,
                              hipStream_t stream) {
  const float* hs = (const float*)d_in[0];
  const float* Wq = (const float*)d_in[1];
  const float* Wk = (const float*)d_in[2];
  const float* Wv = (const float*)d_in[3];
  const float* Wo = (const float*)d_in[4];
  float* out = (float*)d_out;
  char* ws = (char*)d_ws;

  bf16*  hsb   = (bf16*)(ws);                    // 2048x4096 bf16
  bf16*  wqkvb = (bf16*)(ws + 16777216);         // 6144x4096 bf16
  bf16*  wob   = (bf16*)(ws + 67108864);         // 4096x4096 bf16
  bf16*  qkv   = (bf16*)(ws + 100663296);        // 2048x6144 bf16
  bf16*  attn  = (bf16*)(ws + 125829120);        // 2048x4096 bf16
  float* cost  = (float*)(ws + 142606336);       // 2048x64 f32
  float* sint  = (float*)(ws + 143130624);       // 2048x64 f32

  cvt_all_kernel<<<49664, 256, 0, stream>>>(hs, Wq, Wk, Wv, Wo, hsb, wqkvb, wob, cost, sint);
  gemm4p_kernel<3, bf16><<<dim3(32, 8), 512, 0, stream>>>(hsb, wqkvb, qkv, 2048, 6144, 4096);
  rope_apply_kernel<<<2560, 256, 0, stream>>>(qkv, cost, sint);
  attn_kernel<<<512, 512, 0, stream>>>(qkv, attn);
  gemm4p_kernel<2, float><<<dim3(32, 8), 512, 0, stream>>>(attn, wob, out, 2048, 4096, 4096);
}